// Round 18
// baseline (112.033 us; speedup 1.0000x reference)
//
#include <hip/hip_runtime.h>
#include <hip/hip_bf16.h>

typedef float f32x4 __attribute__((ext_vector_type(4)));
typedef __bf16 bf16x8 __attribute__((ext_vector_type(8)));
typedef unsigned short u16;

// Problem dims (fixed): B=128, T=64, H=1024, Hu=512, J=129, N=128, I=64, MJW=64
// ws layout
#define OFF_W1T  0u            // 512x1024 bf16 = 1048576 B  (W1T[n][k] = W1[k][n])
#define OFF_W23B 1048576u      // 144x512 bf16 fragment-order = 147456 B
#define OFF_TS   1196032u      // 8192x512 bf16 = 8388608 B
#define OFF_JWT  9584640u      // 128 x 64(col) x 64(row) f32 = 2097152 B
#define OFF_P0   11681792u     // 8192 f32 = 32768 B

static __device__ __forceinline__ u16 f2bf(float x) {
    __bf16 h = (__bf16)x;
    return __builtin_bit_cast(u16, h);
}

__device__ __forceinline__ void gload16(const void* g, void* l) {
    __builtin_amdgcn_global_load_lds(
        (const __attribute__((address_space(1))) void*)g,
        (__attribute__((address_space(3))) void*)l,
        16, 0, 0);
}

// ---------------------------------------------------------------------------
// prep (unchanged, R16)
// ---------------------------------------------------------------------------
__global__ __launch_bounds__(256) void prep_kernel(
    const float* __restrict__ W1, const float* __restrict__ W2,
    const float* __restrict__ W3,
    __bf16* __restrict__ W1T, __bf16* __restrict__ W23B)
{
    const int t = threadIdx.x;
    if (blockIdx.x < 128) {
        __shared__ __bf16 lds_t[64][72];
        const int kt = blockIdx.x >> 3, nt = blockIdx.x & 7;
        const int k0 = kt * 64, n0 = nt * 64;
        {
            const int kr = t >> 2, c0 = (t & 3) * 16;
            const float* src = W1 + (size_t)(k0 + kr) * 512 + n0 + c0;
            #pragma unroll
            for (int q = 0; q < 4; ++q) {
                float4 v = *(const float4*)(src + q * 4);
                lds_t[kr][c0 + q * 4 + 0] = (__bf16)v.x;
                lds_t[kr][c0 + q * 4 + 1] = (__bf16)v.y;
                lds_t[kr][c0 + q * 4 + 2] = (__bf16)v.z;
                lds_t[kr][c0 + q * 4 + 3] = (__bf16)v.w;
            }
        }
        __syncthreads();
        {
            const int nr = t >> 2, kc = (t & 3) * 16;
            bf16x8 o0, o1;
            #pragma unroll
            for (int j = 0; j < 8; ++j) o0[j] = lds_t[kc + j][nr];
            #pragma unroll
            for (int j = 0; j < 8; ++j) o1[j] = lds_t[kc + 8 + j][nr];
            __bf16* dst = W1T + (size_t)(n0 + nr) * 1024 + k0 + kc;
            *(bf16x8*)(dst)     = o0;
            *(bf16x8*)(dst + 8) = o1;
        }
    } else {
        int g = (blockIdx.x - 128) * 256 + t;   // 0..9215
        if (g < 9216) {
            int n = g >> 6;            // 0..143
            int k8 = (g & 63) * 8;     // 0,8,..,504
            bf16x8 v;
            #pragma unroll
            for (int j = 0; j < 8; ++j) {
                int k = k8 + j;
                float x = 0.0f;
                if (n < 129) x = W2[(size_t)k * 129 + n];
                else if (n == 129) x = W3[k];
                v[j] = (__bf16)x;
            }
            int kk = k8 >> 5, lg = (k8 >> 3) & 3, ct = n >> 4, lr = n & 15;
            *(bf16x8*)&W23B[(((size_t)(kk * 9 + ct)) * 64 + lg * 16 + lr) * 8] = v;
        }
    }
}

// ---------------------------------------------------------------------------
// GEMM1 (unchanged, R16: ring-3, 3 blocks/CU, vmcnt(4), ~22us)
// ---------------------------------------------------------------------------
__global__ __launch_bounds__(256, 3) void gemm1_kernel(
    const float* __restrict__ Y, const __bf16* __restrict__ W1T,
    const float* __restrict__ b1, u16* __restrict__ ts)
{
    __shared__ float  As[3][64 * 32];
    __shared__ __bf16 Bs[3][128 * 32];
    const int tid = threadIdx.x;
    const int bid = blockIdx.x;
    const int half = bid >> 8;
    const int b8 = bid & 255;
    const int xcd = b8 & 7;
    const int ii = b8 >> 3;
    const int rb = half * 64 + xcd * 8 + (ii >> 2);
    const int tb = ii & 3;
    const int m0 = rb * 64, n0 = tb * 128;
    const int wid = tid >> 6, lane = tid & 63;
    const int wr = wid >> 1, wc = wid & 1;
    const int lr = lane & 15, lg = lane >> 4;
    const int al = lane >> 3;
    const int au = (lane & 7) ^ al;
    const float* yA0 = Y + (size_t)(m0 + (wid * 2 + 0) * 8 + al) * 1024 + au * 4;
    const float* yA1 = Y + (size_t)(m0 + (wid * 2 + 1) * 8 + al) * 1024 + au * 4;
    const int bl = lane >> 2;
    const int bu = (lane & 3) ^ ((bl >> 1) & 3);
    const __bf16* wB0 = W1T + (size_t)(n0 + (wid * 2 + 0) * 16 + bl) * 1024 + bu * 8;
    const __bf16* wB1 = W1T + (size_t)(n0 + (wid * 2 + 1) * 16 + bl) * 1024 + bu * 8;

    f32x4 acc[2][4];
    #pragma unroll
    for (int m = 0; m < 2; m++)
        #pragma unroll
        for (int n = 0; n < 4; n++) { f32x4 z = {0.f,0.f,0.f,0.f}; acc[m][n] = z; }

#define STAGE(buf, kt) do { \
    gload16(yA0 + (kt) * 32, &As[buf][(wid * 2 + 0) * 256]); \
    gload16(yA1 + (kt) * 32, &As[buf][(wid * 2 + 1) * 256]); \
    gload16(wB0 + (kt) * 32, &Bs[buf][(wid * 2 + 0) * 512]); \
    gload16(wB1 + (kt) * 32, &Bs[buf][(wid * 2 + 1) * 512]); \
} while (0)

#define COMPUTE(buf) do { \
    bf16x8 af[2]; bf16x8 bfr[4]; \
    _Pragma("unroll") \
    for (int m = 0; m < 2; ++m) { \
        const int row = wr * 32 + m * 16 + lr; \
        const int r7 = row & 7; \
        float4 h0 = *(const float4*)&As[buf][row * 32 + (((lg * 2 + 0) ^ r7) * 4)]; \
        float4 h1 = *(const float4*)&As[buf][row * 32 + (((lg * 2 + 1) ^ r7) * 4)]; \
        bf16x8 tt; \
        tt[0]=(__bf16)h0.x; tt[1]=(__bf16)h0.y; tt[2]=(__bf16)h0.z; tt[3]=(__bf16)h0.w; \
        tt[4]=(__bf16)h1.x; tt[5]=(__bf16)h1.y; tt[6]=(__bf16)h1.z; tt[7]=(__bf16)h1.w; \
        af[m] = tt; \
    } \
    _Pragma("unroll") \
    for (int n = 0; n < 4; ++n) { \
        const int rowb = wc * 64 + n * 16 + lr; \
        bfr[n] = *(const bf16x8*)&Bs[buf][rowb * 32 + ((lg ^ ((rowb >> 1) & 3)) * 8)]; \
    } \
    __builtin_amdgcn_s_setprio(1); \
    _Pragma("unroll") \
    for (int m = 0; m < 2; ++m) \
        _Pragma("unroll") \
        for (int n = 0; n < 4; ++n) \
            acc[m][n] = __builtin_amdgcn_mfma_f32_16x16x32_bf16(af[m], bfr[n], acc[m][n], 0, 0, 0); \
    __builtin_amdgcn_s_setprio(0); \
} while (0)

    STAGE(0, 0); STAGE(1, 1);
    {
        int buf = 0, sbuf = 2;
        #pragma unroll 1
        for (int kt = 0; kt < 30; ++kt) {
            asm volatile("s_waitcnt vmcnt(4)" ::: "memory");
            __builtin_amdgcn_s_barrier();
            COMPUTE(buf);
            STAGE(sbuf, kt + 2);
            buf  = (buf  == 2) ? 0 : buf  + 1;
            sbuf = (sbuf == 2) ? 0 : sbuf + 1;
        }
    }
    asm volatile("s_waitcnt vmcnt(4)" ::: "memory");
    __builtin_amdgcn_s_barrier();
    COMPUTE(0);
    asm volatile("s_waitcnt vmcnt(0)" ::: "memory");
    __builtin_amdgcn_s_barrier();
    COMPUTE(1);

    #pragma unroll
    for (int m = 0; m < 2; m++) {
        #pragma unroll
        for (int n = 0; n < 4; n++) {
            int col = n0 + wc * 64 + n * 16 + lr;
            float bias = b1[col];
            #pragma unroll
            for (int j = 0; j < 4; j++) {
                int row = m0 + wr * 32 + m * 16 + lg * 4 + j;
                float v = tanhf(acc[m][n][j] + bias);
                ts[(size_t)row * 512 + col] = f2bf(v);
            }
        }
    }
#undef STAGE
#undef COMPUTE
}

// ---------------------------------------------------------------------------
// band (unchanged, R16): writes jwT[b][c][k] = M_b[k][c] (f32) and p0.
// ---------------------------------------------------------------------------
__global__ __launch_bounds__(256) void band_kernel(
    const u16* __restrict__ ts, const u16* __restrict__ W23B,
    const float* __restrict__ b2, const float* __restrict__ b3,
    float* __restrict__ jwT, float* __restrict__ p0)
{
    const int b = blockIdx.x;
    const int tid = threadIdx.x;
    const int w = tid >> 6, lane = tid & 63;
    const int lr = lane & 15, lg = lane >> 4;
    const int r0 = b * 64 + w * 16;

    f32x4 acc[9];
    #pragma unroll
    for (int ct = 0; ct < 9; ct++) { f32x4 z = {0.f,0.f,0.f,0.f}; acc[ct] = z; }

    #pragma unroll 4
    for (int kk = 0; kk < 16; ++kk) {
        bf16x8 a = *(const bf16x8*)(ts + (size_t)(r0 + lr) * 512 + kk * 32 + lg * 8);
        #pragma unroll
        for (int ct = 0; ct < 9; ct++) {
            bf16x8 bv = *(const bf16x8*)(W23B + ((size_t)(kk * 9 + ct) * 64 + lane) * 8);
            acc[ct] = __builtin_amdgcn_mfma_f32_16x16x32_bf16(a, bv, acc[ct], 0, 0, 0);
        }
    }

    float b3v = b3[0];
    #pragma unroll
    for (int j = 0; j < 4; j++) {
        int rloc = w * 16 + lg * 4 + j;   // row within batch (0..63)
        float v[9];
        float mx = -1e30f;
        #pragma unroll
        for (int ct = 0; ct < 9; ct++) {
            int col = ct * 16 + lr;
            if (col < 129) { float x = acc[ct][j] + b2[col]; v[ct] = x; mx = fmaxf(mx, x); }
            else v[ct] = -1e30f;
        }
        #pragma unroll
        for (int o = 1; o < 16; o <<= 1) mx = fmaxf(mx, __shfl_xor(mx, o));
        float sum = 0.f;
        #pragma unroll
        for (int ct = 0; ct < 9; ct++) {
            int col = ct * 16 + lr;
            if (col < 129) { float e = expf(v[ct] - mx); v[ct] = e; sum += e; }
        }
        #pragma unroll
        for (int o = 1; o < 16; o <<= 1) sum += __shfl_xor(sum, o);
        float inv = 1.0f / sum;
        #pragma unroll
        for (int ct = 0; ct < 9; ct++) {
            int col = ct * 16 + lr;
            int cc = col - 64 + rloc;
            if (col < 129 && cc >= 0 && cc < 64)
                jwT[((size_t)b * 64 + cc) * 64 + rloc] = v[ct] * inv;
        }
        if (lr == 1) {
            float pv = acc[8][j] + b3v;
            p0[b * 64 + rloc] = 1.0f / (1.0f + expf(-pv));
        }
    }
}

// ---------------------------------------------------------------------------
// recur: ONE WAVE per batch, MFMA matvec. Band fixed in registers as MFMA
// A-operand (afr[mt][kk], 32 VGPR). Per iter: 16 lanes write a (f32) to LDS,
// ALL lanes read the same 8-float slices (uniform -> broadcast) as B operand
// -> every C column computes the same u -> every lane holds all 64 u values
// (no reduce, no barrier). Lazy exponent-flush keyed on m=0 folded into em
// factors (R13 scheme, absmax-0-proven). em pre-transposed in LDS.
// ---------------------------------------------------------------------------
__global__ __launch_bounds__(64, 1) void recur_kernel(
    const float* __restrict__ jwT, const float* __restrict__ p0g,
    const float* __restrict__ em, const int* __restrict__ slen,
    float* __restrict__ out)
{
    __shared__ float emlo_s[64][64];   // [i][m] = em[b][m][i]
    __shared__ float emhi_s[64][64];   // [i][m] = em[b][m+64][i]
    __shared__ float p0_s[64];
    __shared__ float a_s[64];
    const int b = blockIdx.x, lane = threadIdx.x;
    const int lr = lane & 15, lg = lane >> 4;
    const int idx = slen[b] - 1;

    if (idx <= 0) { if (lane == 0) out[b] = 1.0f; return; }

    // A-fragments: afr[mt][kk][j] = A[mt*16+lr][kk*32+lg*8+j] = jwT[b][m][k]
    // (A[m][k] = M^T[m][k] = M[k][m] = jwT[b][m][k]; row layout verified vs band)
    bf16x8 afr[4][2];
    {
        const float* Mrow = jwT + (size_t)b * 4096;
        #pragma unroll
        for (int mt = 0; mt < 4; ++mt)
            #pragma unroll
            for (int kk = 0; kk < 2; ++kk) {
                const float* p = Mrow + (mt * 16 + lr) * 64 + kk * 32 + lg * 8;
                float4 h0 = *(const float4*)(p);
                float4 h1 = *(const float4*)(p + 4);
                bf16x8 tt;
                tt[0]=(__bf16)h0.x; tt[1]=(__bf16)h0.y; tt[2]=(__bf16)h0.z; tt[3]=(__bf16)h0.w;
                tt[4]=(__bf16)h1.x; tt[5]=(__bf16)h1.y; tt[6]=(__bf16)h1.z; tt[7]=(__bf16)h1.w;
                afr[mt][kk] = tt;
            }
    }
    // stage em transposed: lane c handles column m=c (conflict-free writes)
    {
        const float* elo = em + (size_t)b * 8192 + lane * 64;
        const float* ehi = elo + 64 * 64;
        #pragma unroll 4
        for (int q = 0; q < 16; ++q) {
            float4 v = *(const float4*)(elo + q * 4);
            emlo_s[q * 4 + 0][lane] = v.x;
            emlo_s[q * 4 + 1][lane] = v.y;
            emlo_s[q * 4 + 2][lane] = v.z;
            emlo_s[q * 4 + 3][lane] = v.w;
            float4 w = *(const float4*)(ehi + q * 4);
            emhi_s[q * 4 + 0][lane] = w.x;
            emhi_s[q * 4 + 1][lane] = w.y;
            emhi_s[q * 4 + 2][lane] = w.z;
            emhi_s[q * 4 + 3][lane] = w.w;
        }
        p0_s[lane] = p0g[b * 64 + lane];
    }
    __syncthreads();   // single wave: cheap ordering point

    // per-lane m-set: m = mt*16 + lg*4 + j  (C-fragment rows, all cols equal)
    f32x4 p0v[4], aprev[4], elo[4], ehi[4];
    #pragma unroll
    for (int mt = 0; mt < 4; ++mt) {
        const int mb = mt * 16 + lg * 4;
        p0v[mt]  = *(const f32x4*)&p0_s[mb];
        f32x4 e0 = *(const f32x4*)&emlo_s[0][mb];
        f32x4 h0 = *(const f32x4*)&emhi_s[0][mb];
        aprev[mt] = e0 + h0;                       // a0
        elo[mt] = *(const f32x4*)&emlo_s[1][mb];   // em for i=1
        ehi[mt] = *(const f32x4*)&emhi_s[1][mb];
    }

    int Eacc = 0;
    #pragma unroll 1
    for (int i = 1; i <= idx; ++i) {
        // 16 writer lanes (lr<4) store a chunks: chunk (mt=lr, lg) -> disjoint
        if (lr < 4) *(f32x4*)&a_s[lr * 16 + lg * 4] = aprev[lr];
        // uniform broadcast reads of a slices (HW in-order DS: reads follow write)
        bf16x8 bfr[2];
        #pragma unroll
        for (int kk = 0; kk < 2; ++kk) {
            float4 s0 = *(const float4*)&a_s[kk * 32 + lg * 8];
            float4 s1 = *(const float4*)&a_s[kk * 32 + lg * 8 + 4];
            bf16x8 tt;
            tt[0]=(__bf16)s0.x; tt[1]=(__bf16)s0.y; tt[2]=(__bf16)s0.z; tt[3]=(__bf16)s0.w;
            tt[4]=(__bf16)s1.x; tt[5]=(__bf16)s1.y; tt[6]=(__bf16)s1.z; tt[7]=(__bf16)s1.w;
            bfr[kk] = tt;
        }
        // prefetch next-iter em
        const int ip = (i < 63) ? (i + 1) : 63;
        f32x4 nlo[4], nhi[4];
        #pragma unroll
        for (int mt = 0; mt < 4; ++mt) {
            const int mb = mt * 16 + lg * 4;
            nlo[mt] = *(const f32x4*)&emlo_s[ip][mb];
            nhi[mt] = *(const f32x4*)&emhi_s[ip][mb];
        }
        // exponent-flush keyed on m=0 (lane 0's aprev[0][0]); scales folded into em
        int bits = __builtin_amdgcn_readfirstlane(__float_as_int(aprev[0][0]));
        int ef = (bits >> 23) & 255;
        Eacc += ef - 127;
        float s = __int_as_float((254 - ef) << 23);   // 2^(127-ef), exact
        // MFMA matvec: u = M^T a   (A fixed in regs, B = broadcast a)
        f32x4 u[4];
        #pragma unroll
        for (int mt = 0; mt < 4; ++mt) { f32x4 z = {0.f,0.f,0.f,0.f}; u[mt] = z; }
        #pragma unroll
        for (int kk = 0; kk < 2; ++kk)
            #pragma unroll
            for (int mt = 0; mt < 4; ++mt)
                u[mt] = __builtin_amdgcn_mfma_f32_16x16x32_bf16(afr[mt][kk], bfr[kk], u[mt], 0, 0, 0);
        // epilogue: u = u*(emlo*s) + aprev*(p0*emhi*s)
        #pragma unroll
        for (int mt = 0; mt < 4; ++mt) {
            f32x4 el = elo[mt] * s;
            f32x4 eh = ehi[mt] * s;
            u[mt] = u[mt] * el + (aprev[mt] * p0v[mt]) * eh;
            aprev[mt] = u[mt];
            elo[mt] = nlo[mt]; ehi[mt] = nhi[mt];
        }
    }
    // every lane holds all 64 components exactly once -> lane-local total
    float r = 0.f;
    #pragma unroll
    for (int mt = 0; mt < 4; ++mt)
        r += (aprev[mt][0] + aprev[mt][1]) + (aprev[mt][2] + aprev[mt][3]);
    if (lane == 0)
        out[b] = 1.0f + 0.6931471805599453f *
                 ((float)Eacc + __log2f(r) + 7.0f * (float)idx);
}

extern "C" void kernel_launch(void* const* d_in, const int* in_sizes, int n_in,
                              void* d_out, int out_size, void* d_ws, size_t ws_size,
                              hipStream_t stream)
{
    const float* Y   = (const float*)d_in[0];
    const float* em  = (const float*)d_in[1];
    const int*   sl  = (const int*)d_in[2];
    const float* W1  = (const float*)d_in[3];
    const float* b1  = (const float*)d_in[4];
    const float* W2  = (const float*)d_in[5];
    const float* b2  = (const float*)d_in[6];
    const float* W3  = (const float*)d_in[7];
    const float* b3  = (const float*)d_in[8];
    float* out = (float*)d_out;
    char* ws = (char*)d_ws;

    __bf16* W1T  = (__bf16*)(ws + OFF_W1T);
    __bf16* W23B = (__bf16*)(ws + OFF_W23B);
    u16*    ts   = (u16*)(ws + OFF_TS);
    float*  jwT  = (float*)(ws + OFF_JWT);
    float*  p0   = (float*)(ws + OFF_P0);

    prep_kernel<<<164, 256, 0, stream>>>(W1, W2, W3, W1T, W23B);
    gemm1_kernel<<<512, 256, 0, stream>>>(Y, W1T, b1, ts);
    band_kernel<<<128, 256, 0, stream>>>(ts, (const u16*)W23B, b2, b3, jwT, p0);
    recur_kernel<<<128, 64, 0, stream>>>(jwT, p0, em, sl, out);
}

// Round 19
// 76.122 us; speedup vs baseline: 1.4718x; 1.4718x over previous
//
#include <hip/hip_runtime.h>
#include <hip/hip_bf16.h>

typedef float f32x4 __attribute__((ext_vector_type(4)));
typedef __bf16 bf16x8 __attribute__((ext_vector_type(8)));
typedef unsigned short u16;

// Problem dims (fixed): B=128, T=64, H=1024, Hu=512, J=129, N=128, I=64, MJW=64
// ws layout
#define OFF_W1T  0u            // 512x1024 bf16 = 1048576 B  (W1T[n][k] = W1[k][n])
#define OFF_W23B 1048576u      // 144x512 bf16 fragment-order = 147456 B
#define OFF_TS   1196032u      // 8192x512 bf16 = 8388608 B
#define OFF_JWT  9584640u      // 128 x 64(col) x 64(row) f32 = 2097152 B
#define OFF_P0   11681792u     // 8192 f32 = 32768 B

static __device__ __forceinline__ u16 f2bf(float x) {
    __bf16 h = (__bf16)x;
    return __builtin_bit_cast(u16, h);
}

__device__ __forceinline__ void gload16(const void* g, void* l) {
    __builtin_amdgcn_global_load_lds(
        (const __attribute__((address_space(1))) void*)g,
        (__attribute__((address_space(3))) void*)l,
        16, 0, 0);
}

// ---------------------------------------------------------------------------
// prep (unchanged)
// ---------------------------------------------------------------------------
__global__ __launch_bounds__(256) void prep_kernel(
    const float* __restrict__ W1, const float* __restrict__ W2,
    const float* __restrict__ W3,
    __bf16* __restrict__ W1T, __bf16* __restrict__ W23B)
{
    const int t = threadIdx.x;
    if (blockIdx.x < 128) {
        __shared__ __bf16 lds_t[64][72];
        const int kt = blockIdx.x >> 3, nt = blockIdx.x & 7;
        const int k0 = kt * 64, n0 = nt * 64;
        {
            const int kr = t >> 2, c0 = (t & 3) * 16;
            const float* src = W1 + (size_t)(k0 + kr) * 512 + n0 + c0;
            #pragma unroll
            for (int q = 0; q < 4; ++q) {
                float4 v = *(const float4*)(src + q * 4);
                lds_t[kr][c0 + q * 4 + 0] = (__bf16)v.x;
                lds_t[kr][c0 + q * 4 + 1] = (__bf16)v.y;
                lds_t[kr][c0 + q * 4 + 2] = (__bf16)v.z;
                lds_t[kr][c0 + q * 4 + 3] = (__bf16)v.w;
            }
        }
        __syncthreads();
        {
            const int nr = t >> 2, kc = (t & 3) * 16;
            bf16x8 o0, o1;
            #pragma unroll
            for (int j = 0; j < 8; ++j) o0[j] = lds_t[kc + j][nr];
            #pragma unroll
            for (int j = 0; j < 8; ++j) o1[j] = lds_t[kc + 8 + j][nr];
            __bf16* dst = W1T + (size_t)(n0 + nr) * 1024 + k0 + kc;
            *(bf16x8*)(dst)     = o0;
            *(bf16x8*)(dst + 8) = o1;
        }
    } else {
        int g = (blockIdx.x - 128) * 256 + t;   // 0..9215
        if (g < 9216) {
            int n = g >> 6;            // 0..143
            int k8 = (g & 63) * 8;     // 0,8,..,504
            bf16x8 v;
            #pragma unroll
            for (int j = 0; j < 8; ++j) {
                int k = k8 + j;
                float x = 0.0f;
                if (n < 129) x = W2[(size_t)k * 129 + n];
                else if (n == 129) x = W3[k];
                v[j] = (__bf16)x;
            }
            int kk = k8 >> 5, lg = (k8 >> 3) & 3, ct = n >> 4, lr = n & 15;
            *(bf16x8*)&W23B[(((size_t)(kk * 9 + ct)) * 64 + lg * 16 + lr) * 8] = v;
        }
    }
}

// ---------------------------------------------------------------------------
// GEMM1 (R16/R14-measured ~22us: ring-3, 3 blocks/CU, stage-dist-2, vmcnt(4),
// 1 barrier/step, XCD-chunk swizzle, T21 both-sides swizzles)
// ---------------------------------------------------------------------------
__global__ __launch_bounds__(256, 3) void gemm1_kernel(
    const float* __restrict__ Y, const __bf16* __restrict__ W1T,
    const float* __restrict__ b1, u16* __restrict__ ts)
{
    __shared__ float  As[3][64 * 32];
    __shared__ __bf16 Bs[3][128 * 32];
    const int tid = threadIdx.x;
    const int bid = blockIdx.x;
    const int half = bid >> 8;
    const int b8 = bid & 255;
    const int xcd = b8 & 7;
    const int ii = b8 >> 3;
    const int rb = half * 64 + xcd * 8 + (ii >> 2);
    const int tb = ii & 3;
    const int m0 = rb * 64, n0 = tb * 128;
    const int wid = tid >> 6, lane = tid & 63;
    const int wr = wid >> 1, wc = wid & 1;
    const int lr = lane & 15, lg = lane >> 4;
    const int al = lane >> 3;
    const int au = (lane & 7) ^ al;
    const float* yA0 = Y + (size_t)(m0 + (wid * 2 + 0) * 8 + al) * 1024 + au * 4;
    const float* yA1 = Y + (size_t)(m0 + (wid * 2 + 1) * 8 + al) * 1024 + au * 4;
    const int bl = lane >> 2;
    const int bu = (lane & 3) ^ ((bl >> 1) & 3);
    const __bf16* wB0 = W1T + (size_t)(n0 + (wid * 2 + 0) * 16 + bl) * 1024 + bu * 8;
    const __bf16* wB1 = W1T + (size_t)(n0 + (wid * 2 + 1) * 16 + bl) * 1024 + bu * 8;

    f32x4 acc[2][4];
    #pragma unroll
    for (int m = 0; m < 2; m++)
        #pragma unroll
        for (int n = 0; n < 4; n++) { f32x4 z = {0.f,0.f,0.f,0.f}; acc[m][n] = z; }

#define STAGE(buf, kt) do { \
    gload16(yA0 + (kt) * 32, &As[buf][(wid * 2 + 0) * 256]); \
    gload16(yA1 + (kt) * 32, &As[buf][(wid * 2 + 1) * 256]); \
    gload16(wB0 + (kt) * 32, &Bs[buf][(wid * 2 + 0) * 512]); \
    gload16(wB1 + (kt) * 32, &Bs[buf][(wid * 2 + 1) * 512]); \
} while (0)

#define COMPUTE(buf) do { \
    bf16x8 af[2]; bf16x8 bfr[4]; \
    _Pragma("unroll") \
    for (int m = 0; m < 2; ++m) { \
        const int row = wr * 32 + m * 16 + lr; \
        const int r7 = row & 7; \
        float4 h0 = *(const float4*)&As[buf][row * 32 + (((lg * 2 + 0) ^ r7) * 4)]; \
        float4 h1 = *(const float4*)&As[buf][row * 32 + (((lg * 2 + 1) ^ r7) * 4)]; \
        bf16x8 tt; \
        tt[0]=(__bf16)h0.x; tt[1]=(__bf16)h0.y; tt[2]=(__bf16)h0.z; tt[3]=(__bf16)h0.w; \
        tt[4]=(__bf16)h1.x; tt[5]=(__bf16)h1.y; tt[6]=(__bf16)h1.z; tt[7]=(__bf16)h1.w; \
        af[m] = tt; \
    } \
    _Pragma("unroll") \
    for (int n = 0; n < 4; ++n) { \
        const int rowb = wc * 64 + n * 16 + lr; \
        bfr[n] = *(const bf16x8*)&Bs[buf][rowb * 32 + ((lg ^ ((rowb >> 1) & 3)) * 8)]; \
    } \
    __builtin_amdgcn_s_setprio(1); \
    _Pragma("unroll") \
    for (int m = 0; m < 2; ++m) \
        _Pragma("unroll") \
        for (int n = 0; n < 4; ++n) \
            acc[m][n] = __builtin_amdgcn_mfma_f32_16x16x32_bf16(af[m], bfr[n], acc[m][n], 0, 0, 0); \
    __builtin_amdgcn_s_setprio(0); \
} while (0)

    STAGE(0, 0); STAGE(1, 1);
    {
        int buf = 0, sbuf = 2;
        #pragma unroll 1
        for (int kt = 0; kt < 30; ++kt) {
            asm volatile("s_waitcnt vmcnt(4)" ::: "memory");
            __builtin_amdgcn_s_barrier();
            COMPUTE(buf);
            STAGE(sbuf, kt + 2);
            buf  = (buf  == 2) ? 0 : buf  + 1;
            sbuf = (sbuf == 2) ? 0 : sbuf + 1;
        }
    }
    asm volatile("s_waitcnt vmcnt(4)" ::: "memory");
    __builtin_amdgcn_s_barrier();
    COMPUTE(0);
    asm volatile("s_waitcnt vmcnt(0)" ::: "memory");
    __builtin_amdgcn_s_barrier();
    COMPUTE(1);

    #pragma unroll
    for (int m = 0; m < 2; m++) {
        #pragma unroll
        for (int n = 0; n < 4; n++) {
            int col = n0 + wc * 64 + n * 16 + lr;
            float bias = b1[col];
            #pragma unroll
            for (int j = 0; j < 4; j++) {
                int row = m0 + wr * 32 + m * 16 + lg * 4 + j;
                float v = tanhf(acc[m][n][j] + bias);
                ts[(size_t)row * 512 + col] = f2bf(v);
            }
        }
    }
#undef STAGE
#undef COMPUTE
}

// ---------------------------------------------------------------------------
// band (unchanged): writes jwT[b][c][k] = M_b[k][c] (f32) and p0.
// ---------------------------------------------------------------------------
__global__ __launch_bounds__(256) void band_kernel(
    const u16* __restrict__ ts, const u16* __restrict__ W23B,
    const float* __restrict__ b2, const float* __restrict__ b3,
    float* __restrict__ jwT, float* __restrict__ p0)
{
    const int b = blockIdx.x;
    const int tid = threadIdx.x;
    const int w = tid >> 6, lane = tid & 63;
    const int lr = lane & 15, lg = lane >> 4;
    const int r0 = b * 64 + w * 16;

    f32x4 acc[9];
    #pragma unroll
    for (int ct = 0; ct < 9; ct++) { f32x4 z = {0.f,0.f,0.f,0.f}; acc[ct] = z; }

    #pragma unroll 4
    for (int kk = 0; kk < 16; ++kk) {
        bf16x8 a = *(const bf16x8*)(ts + (size_t)(r0 + lr) * 512 + kk * 32 + lg * 8);
        #pragma unroll
        for (int ct = 0; ct < 9; ct++) {
            bf16x8 bv = *(const bf16x8*)(W23B + ((size_t)(kk * 9 + ct) * 64 + lane) * 8);
            acc[ct] = __builtin_amdgcn_mfma_f32_16x16x32_bf16(a, bv, acc[ct], 0, 0, 0);
        }
    }

    float b3v = b3[0];
    #pragma unroll
    for (int j = 0; j < 4; j++) {
        int rloc = w * 16 + lg * 4 + j;   // row within batch (0..63)
        float v[9];
        float mx = -1e30f;
        #pragma unroll
        for (int ct = 0; ct < 9; ct++) {
            int col = ct * 16 + lr;
            if (col < 129) { float x = acc[ct][j] + b2[col]; v[ct] = x; mx = fmaxf(mx, x); }
            else v[ct] = -1e30f;
        }
        #pragma unroll
        for (int o = 1; o < 16; o <<= 1) mx = fmaxf(mx, __shfl_xor(mx, o));
        float sum = 0.f;
        #pragma unroll
        for (int ct = 0; ct < 9; ct++) {
            int col = ct * 16 + lr;
            if (col < 129) { float e = expf(v[ct] - mx); v[ct] = e; sum += e; }
        }
        #pragma unroll
        for (int o = 1; o < 16; o <<= 1) sum += __shfl_xor(sum, o);
        float inv = 1.0f / sum;
        #pragma unroll
        for (int ct = 0; ct < 9; ct++) {
            int col = ct * 16 + lr;
            int cc = col - 64 + rloc;
            if (col < 129 && cc >= 0 && cc < 64)
                jwT[((size_t)b * 64 + cc) * 64 + rloc] = v[ct] * inv;
        }
        if (lr == 1) {
            float pv = acc[8][j] + b3v;
            p0[b * 64 + rloc] = 1.0f / (1.0f + expf(-pv));
        }
    }
}

// ---------------------------------------------------------------------------
// recur: EXACT R13 version (best measured of the serial family, absmax 0).
// One block = one batch, 64 threads. Raw state to LDS + 16 broadcast
// ds_read_b128 in one asm cluster (no mid-wait); lazy exponent-flush
// computed while reads are in flight, folded into this iter's em factors;
// vector FMAs; em prefetch via compiler loads at end of body.
// ---------------------------------------------------------------------------
__global__ __launch_bounds__(64, 1) void recur_kernel(
    const float* __restrict__ jwT, const float* __restrict__ p0g,
    const float* __restrict__ em, const int* __restrict__ slen,
    float* __restrict__ out)
{
    __shared__ float em_s[128][65];
    __shared__ f32x4 a_bc4[16];
    const int b = blockIdx.x, c = threadIdx.x;

    const float* bb = jwT + ((size_t)b * 64 + c) * 64;
    f32x4 B0  = *(const f32x4*)(bb + 0);
    f32x4 B1  = *(const f32x4*)(bb + 4);
    f32x4 B2  = *(const f32x4*)(bb + 8);
    f32x4 B3  = *(const f32x4*)(bb + 12);
    f32x4 B4  = *(const f32x4*)(bb + 16);
    f32x4 B5  = *(const f32x4*)(bb + 20);
    f32x4 B6  = *(const f32x4*)(bb + 24);
    f32x4 B7  = *(const f32x4*)(bb + 28);
    f32x4 B8  = *(const f32x4*)(bb + 32);
    f32x4 B9  = *(const f32x4*)(bb + 36);
    f32x4 B10 = *(const f32x4*)(bb + 40);
    f32x4 B11 = *(const f32x4*)(bb + 44);
    f32x4 B12 = *(const f32x4*)(bb + 48);
    f32x4 B13 = *(const f32x4*)(bb + 52);
    f32x4 B14 = *(const f32x4*)(bb + 56);
    f32x4 B15 = *(const f32x4*)(bb + 60);

    {
        const float4* eg = (const float4*)(em + (size_t)b * 8192);
        #pragma unroll 8
        for (int q = 0; q < 32; ++q) {
            int i4 = c + q * 64;
            float4 v = eg[i4];
            int base = i4 * 4; int n = base >> 6; int ii = base & 63;
            em_s[n][ii] = v.x; em_s[n][ii + 1] = v.y; em_s[n][ii + 2] = v.z; em_s[n][ii + 3] = v.w;
        }
    }
    const float p0r = p0g[b * 64 + c];
    const int idx = slen[b] - 1;
    __syncthreads();

    float ut = em_s[c][0] + em_s[c + 64][0];   // raw state
    int Eacc = 0;

    unsigned rbase = (unsigned)(uintptr_t)(__attribute__((address_space(3))) void*)&a_bc4[0];
    unsigned waddr = rbase + (unsigned)c * 4u;

    float em_lo = em_s[c][1];       // prefetched for i=1
    float em_hi = em_s[c + 64][1];

    #pragma unroll 1
    for (int i = 1; i <= idx; ++i) {
        // issue write of RAW state + all 16 broadcast reads, NO wait yet
        f32x4 A0,A1,A2,A3,A4,A5,A6,A7,A8,A9,A10,A11,A12,A13,A14,A15;
        asm volatile(
            "ds_write_b32 %17, %16\n\t"
            "ds_read_b128 %0, %18 offset:0\n\t"
            "ds_read_b128 %1, %18 offset:16\n\t"
            "ds_read_b128 %2, %18 offset:32\n\t"
            "ds_read_b128 %3, %18 offset:48\n\t"
            "ds_read_b128 %4, %18 offset:64\n\t"
            "ds_read_b128 %5, %18 offset:80\n\t"
            "ds_read_b128 %6, %18 offset:96\n\t"
            "ds_read_b128 %7, %18 offset:112\n\t"
            "ds_read_b128 %8, %18 offset:128\n\t"
            "ds_read_b128 %9, %18 offset:144\n\t"
            "ds_read_b128 %10, %18 offset:160\n\t"
            "ds_read_b128 %11, %18 offset:176\n\t"
            "ds_read_b128 %12, %18 offset:192\n\t"
            "ds_read_b128 %13, %18 offset:208\n\t"
            "ds_read_b128 %14, %18 offset:224\n\t"
            "ds_read_b128 %15, %18 offset:240"
            : "=&v"(A0), "=&v"(A1), "=&v"(A2),  "=&v"(A3),
              "=&v"(A4), "=&v"(A5), "=&v"(A6),  "=&v"(A7),
              "=&v"(A8), "=&v"(A9), "=&v"(A10), "=&v"(A11),
              "=&v"(A12),"=&v"(A13),"=&v"(A14), "=&v"(A15)
            : "v"(ut), "v"(waddr), "v"(rbase)
            : "memory");
        // flush (overlaps DS latency): scale folded into this iter's em
        int bits = __builtin_amdgcn_readfirstlane(__float_as_int(ut));
        int ef = (bits >> 23) & 255;
        Eacc += ef - 127;
        float scale = __int_as_float((254 - ef) << 23);   // 2^(127-ef), exact
        float emlo_eff = em_lo * scale;
        float emhi_eff = em_hi * p0r * scale;
        // now wait for the broadcasts; fence so FMAs cannot hoist above
        asm volatile("s_waitcnt lgkmcnt(0)" ::: "memory");
        __builtin_amdgcn_sched_barrier(0);
        f32x4 va = A0 * B0;
        f32x4 vb = A1 * B1;
        f32x4 vc = A2 * B2;
        f32x4 vd = A3 * B3;
        va = va + A4 * B4;   vb = vb + A5 * B5;
        vc = vc + A6 * B6;   vd = vd + A7 * B7;
        va = va + A8 * B8;   vb = vb + A9 * B9;
        vc = vc + A10 * B10; vd = vd + A11 * B11;
        va = va + A12 * B12; vb = vb + A13 * B13;
        vc = vc + A14 * B14; vd = vd + A15 * B15;
        f32x4 vs = (va + vb) + (vc + vd);
        float sum = (vs[0] + vs[1]) + (vs[2] + vs[3]);
        ut = sum * emlo_eff + ut * emhi_eff;   // raw_i
        // prefetch next-iter em (pad col 64 makes i+1=64 safe)
        em_lo = em_s[c][i + 1];
        em_hi = em_s[c + 64][i + 1];
    }
    // final reduce on RAW state; last flush intentionally not applied
    float r = ut;
    #pragma unroll
    for (int o = 1; o < 64; o <<= 1) r += __shfl_xor(r, o);
    if (c == 0) {
        float res = 1.0f;
        if (idx > 0)
            res = 1.0f + 0.6931471805599453f * ((float)Eacc + __log2f(r) + 7.0f * (float)idx);
        out[b] = res;
    }
}

extern "C" void kernel_launch(void* const* d_in, const int* in_sizes, int n_in,
                              void* d_out, int out_size, void* d_ws, size_t ws_size,
                              hipStream_t stream)
{
    const float* Y   = (const float*)d_in[0];
    const float* em  = (const float*)d_in[1];
    const int*   sl  = (const int*)d_in[2];
    const float* W1  = (const float*)d_in[3];
    const float* b1  = (const float*)d_in[4];
    const float* W2  = (const float*)d_in[5];
    const float* b2  = (const float*)d_in[6];
    const float* W3  = (const float*)d_in[7];
    const float* b3  = (const float*)d_in[8];
    float* out = (float*)d_out;
    char* ws = (char*)d_ws;

    __bf16* W1T  = (__bf16*)(ws + OFF_W1T);
    __bf16* W23B = (__bf16*)(ws + OFF_W23B);
    u16*    ts   = (u16*)(ws + OFF_TS);
    float*  jwT  = (float*)(ws + OFF_JWT);
    float*  p0   = (float*)(ws + OFF_P0);

    prep_kernel<<<164, 256, 0, stream>>>(W1, W2, W3, W1T, W23B);
    gemm1_kernel<<<512, 256, 0, stream>>>(Y, W1T, b1, ts);
    band_kernel<<<128, 256, 0, stream>>>(ts, (const u16*)W23B, b2, b3, jwT, p0);
    recur_kernel<<<128, 64, 0, stream>>>(jwT, p0, em, sl, out);
}

// Round 20
// 72.346 us; speedup vs baseline: 1.5486x; 1.0522x over previous
//
#include <hip/hip_runtime.h>
#include <hip/hip_bf16.h>

typedef float f32x4 __attribute__((ext_vector_type(4)));
typedef __bf16 bf16x8 __attribute__((ext_vector_type(8)));
typedef unsigned short u16;

// Problem dims (fixed): B=128, T=64, H=1024, Hu=512, J=129, N=128, I=64, MJW=64
// ws layout
#define OFF_W1T  0u            // 512x1024 bf16 = 1048576 B  (W1T[n][k] = W1[k][n])
#define OFF_W23B 1048576u      // 144x512 bf16 fragment-order = 147456 B
#define OFF_TS   1196032u      // 8192x512 bf16 = 8388608 B

static __device__ __forceinline__ u16 f2bf(float x) {
    __bf16 h = (__bf16)x;
    return __builtin_bit_cast(u16, h);
}

__device__ __forceinline__ void gload16(const void* g, void* l) {
    __builtin_amdgcn_global_load_lds(
        (const __attribute__((address_space(1))) void*)g,
        (__attribute__((address_space(3))) void*)l,
        16, 0, 0);
}

// ---------------------------------------------------------------------------
// prep (unchanged)
// ---------------------------------------------------------------------------
__global__ __launch_bounds__(256) void prep_kernel(
    const float* __restrict__ W1, const float* __restrict__ W2,
    const float* __restrict__ W3,
    __bf16* __restrict__ W1T, __bf16* __restrict__ W23B)
{
    const int t = threadIdx.x;
    if (blockIdx.x < 128) {
        __shared__ __bf16 lds_t[64][72];
        const int kt = blockIdx.x >> 3, nt = blockIdx.x & 7;
        const int k0 = kt * 64, n0 = nt * 64;
        {
            const int kr = t >> 2, c0 = (t & 3) * 16;
            const float* src = W1 + (size_t)(k0 + kr) * 512 + n0 + c0;
            #pragma unroll
            for (int q = 0; q < 4; ++q) {
                float4 v = *(const float4*)(src + q * 4);
                lds_t[kr][c0 + q * 4 + 0] = (__bf16)v.x;
                lds_t[kr][c0 + q * 4 + 1] = (__bf16)v.y;
                lds_t[kr][c0 + q * 4 + 2] = (__bf16)v.z;
                lds_t[kr][c0 + q * 4 + 3] = (__bf16)v.w;
            }
        }
        __syncthreads();
        {
            const int nr = t >> 2, kc = (t & 3) * 16;
            bf16x8 o0, o1;
            #pragma unroll
            for (int j = 0; j < 8; ++j) o0[j] = lds_t[kc + j][nr];
            #pragma unroll
            for (int j = 0; j < 8; ++j) o1[j] = lds_t[kc + 8 + j][nr];
            __bf16* dst = W1T + (size_t)(n0 + nr) * 1024 + k0 + kc;
            *(bf16x8*)(dst)     = o0;
            *(bf16x8*)(dst + 8) = o1;
        }
    } else {
        int g = (blockIdx.x - 128) * 256 + t;   // 0..9215
        if (g < 9216) {
            int n = g >> 6;            // 0..143
            int k8 = (g & 63) * 8;     // 0,8,..,504
            bf16x8 v;
            #pragma unroll
            for (int j = 0; j < 8; ++j) {
                int k = k8 + j;
                float x = 0.0f;
                if (n < 129) x = W2[(size_t)k * 129 + n];
                else if (n == 129) x = W3[k];
                v[j] = (__bf16)x;
            }
            int kk = k8 >> 5, lg = (k8 >> 3) & 3, ct = n >> 4, lr = n & 15;
            *(bf16x8*)&W23B[(((size_t)(kk * 9 + ct)) * 64 + lg * 16 + lr) * 8] = v;
        }
    }
}

// ---------------------------------------------------------------------------
// GEMM1 (unchanged from R19: ring-3, 3 blocks/CU, stage-dist-2, vmcnt(4),
// 1 barrier/step, XCD-chunk swizzle, T21 both-sides swizzles; ~22us)
// ---------------------------------------------------------------------------
__global__ __launch_bounds__(256, 3) void gemm1_kernel(
    const float* __restrict__ Y, const __bf16* __restrict__ W1T,
    const float* __restrict__ b1, u16* __restrict__ ts)
{
    __shared__ float  As[3][64 * 32];
    __shared__ __bf16 Bs[3][128 * 32];
    const int tid = threadIdx.x;
    const int bid = blockIdx.x;
    const int half = bid >> 8;
    const int b8 = bid & 255;
    const int xcd = b8 & 7;
    const int ii = b8 >> 3;
    const int rb = half * 64 + xcd * 8 + (ii >> 2);
    const int tb = ii & 3;
    const int m0 = rb * 64, n0 = tb * 128;
    const int wid = tid >> 6, lane = tid & 63;
    const int wr = wid >> 1, wc = wid & 1;
    const int lr = lane & 15, lg = lane >> 4;
    const int al = lane >> 3;
    const int au = (lane & 7) ^ al;
    const float* yA0 = Y + (size_t)(m0 + (wid * 2 + 0) * 8 + al) * 1024 + au * 4;
    const float* yA1 = Y + (size_t)(m0 + (wid * 2 + 1) * 8 + al) * 1024 + au * 4;
    const int bl = lane >> 2;
    const int bu = (lane & 3) ^ ((bl >> 1) & 3);
    const __bf16* wB0 = W1T + (size_t)(n0 + (wid * 2 + 0) * 16 + bl) * 1024 + bu * 8;
    const __bf16* wB1 = W1T + (size_t)(n0 + (wid * 2 + 1) * 16 + bl) * 1024 + bu * 8;

    f32x4 acc[2][4];
    #pragma unroll
    for (int m = 0; m < 2; m++)
        #pragma unroll
        for (int n = 0; n < 4; n++) { f32x4 z = {0.f,0.f,0.f,0.f}; acc[m][n] = z; }

#define STAGE(buf, kt) do { \
    gload16(yA0 + (kt) * 32, &As[buf][(wid * 2 + 0) * 256]); \
    gload16(yA1 + (kt) * 32, &As[buf][(wid * 2 + 1) * 256]); \
    gload16(wB0 + (kt) * 32, &Bs[buf][(wid * 2 + 0) * 512]); \
    gload16(wB1 + (kt) * 32, &Bs[buf][(wid * 2 + 1) * 512]); \
} while (0)

#define COMPUTE(buf) do { \
    bf16x8 af[2]; bf16x8 bfr[4]; \
    _Pragma("unroll") \
    for (int m = 0; m < 2; ++m) { \
        const int row = wr * 32 + m * 16 + lr; \
        const int r7 = row & 7; \
        float4 h0 = *(const float4*)&As[buf][row * 32 + (((lg * 2 + 0) ^ r7) * 4)]; \
        float4 h1 = *(const float4*)&As[buf][row * 32 + (((lg * 2 + 1) ^ r7) * 4)]; \
        bf16x8 tt; \
        tt[0]=(__bf16)h0.x; tt[1]=(__bf16)h0.y; tt[2]=(__bf16)h0.z; tt[3]=(__bf16)h0.w; \
        tt[4]=(__bf16)h1.x; tt[5]=(__bf16)h1.y; tt[6]=(__bf16)h1.z; tt[7]=(__bf16)h1.w; \
        af[m] = tt; \
    } \
    _Pragma("unroll") \
    for (int n = 0; n < 4; ++n) { \
        const int rowb = wc * 64 + n * 16 + lr; \
        bfr[n] = *(const bf16x8*)&Bs[buf][rowb * 32 + ((lg ^ ((rowb >> 1) & 3)) * 8)]; \
    } \
    __builtin_amdgcn_s_setprio(1); \
    _Pragma("unroll") \
    for (int m = 0; m < 2; ++m) \
        _Pragma("unroll") \
        for (int n = 0; n < 4; ++n) \
            acc[m][n] = __builtin_amdgcn_mfma_f32_16x16x32_bf16(af[m], bfr[n], acc[m][n], 0, 0, 0); \
    __builtin_amdgcn_s_setprio(0); \
} while (0)

    STAGE(0, 0); STAGE(1, 1);
    {
        int buf = 0, sbuf = 2;
        #pragma unroll 1
        for (int kt = 0; kt < 30; ++kt) {
            asm volatile("s_waitcnt vmcnt(4)" ::: "memory");
            __builtin_amdgcn_s_barrier();
            COMPUTE(buf);
            STAGE(sbuf, kt + 2);
            buf  = (buf  == 2) ? 0 : buf  + 1;
            sbuf = (sbuf == 2) ? 0 : sbuf + 1;
        }
    }
    asm volatile("s_waitcnt vmcnt(4)" ::: "memory");
    __builtin_amdgcn_s_barrier();
    COMPUTE(0);
    asm volatile("s_waitcnt vmcnt(0)" ::: "memory");
    __builtin_amdgcn_s_barrier();
    COMPUTE(1);

    #pragma unroll
    for (int m = 0; m < 2; m++) {
        #pragma unroll
        for (int n = 0; n < 4; n++) {
            int col = n0 + wc * 64 + n * 16 + lr;
            float bias = b1[col];
            #pragma unroll
            for (int j = 0; j < 4; j++) {
                int row = m0 + wr * 32 + m * 16 + lg * 4 + j;
                float v = tanhf(acc[m][n][j] + bias);
                ts[(size_t)row * 512 + col] = f2bf(v);
            }
        }
    }
#undef STAGE
#undef COMPUTE
}

// ---------------------------------------------------------------------------
// FUSED band + recur. One block = one batch, 256 threads.
// Phase 1 (4 waves): GEMM2+softmax+sigmoid -> transposed band jwT_s[c][k]
// (pad 65) and p0_s in LDS; em staged to em_s concurrently (overlaps GEMM).
// Phase 2 (wave 0): EXACT R19 recur loop -- asm DS-broadcast cluster, lazy
// exponent-flush folded into em factors, vector FMAs. B regs from jwT_s rows
// (stride-65 -> 2-way bank access, free). Saves one dispatch + 4.2MB global
// round-trip vs the split version.
// ---------------------------------------------------------------------------
__global__ __launch_bounds__(256, 1) void band_recur_kernel(
    const u16* __restrict__ ts, const u16* __restrict__ W23B,
    const float* __restrict__ b2, const float* __restrict__ b3,
    const float* __restrict__ em, const int* __restrict__ slen,
    float* __restrict__ out)
{
    __shared__ float jwT_s[64][65];   // [c][k] = M[k][c] (pre-shifted transposed band)
    __shared__ float em_s[128][65];
    __shared__ float p0_s[64];
    __shared__ f32x4 a_bc4[16];
    const int b = blockIdx.x;
    const int tid = threadIdx.x;
    const int w = tid >> 6, lane = tid & 63;
    const int lr = lane & 15, lg = lane >> 4;
    const int r0 = b * 64 + w * 16;

    // stage emission (independent of the GEMM; overlaps it)
    {
        const float4* eg = (const float4*)(em + (size_t)b * 8192);
        #pragma unroll
        for (int q = 0; q < 8; ++q) {
            int i4 = tid + q * 256;
            float4 v = eg[i4];
            int base = i4 * 4; int n = base >> 6; int ii = base & 63;
            em_s[n][ii] = v.x; em_s[n][ii + 1] = v.y; em_s[n][ii + 2] = v.z; em_s[n][ii + 3] = v.w;
        }
    }

    f32x4 acc[9];
    #pragma unroll
    for (int ct = 0; ct < 9; ct++) { f32x4 z = {0.f,0.f,0.f,0.f}; acc[ct] = z; }

    #pragma unroll 4
    for (int kk = 0; kk < 16; ++kk) {
        bf16x8 a = *(const bf16x8*)(ts + (size_t)(r0 + lr) * 512 + kk * 32 + lg * 8);
        #pragma unroll
        for (int ct = 0; ct < 9; ct++) {
            bf16x8 bv = *(const bf16x8*)(W23B + ((size_t)(kk * 9 + ct) * 64 + lane) * 8);
            acc[ct] = __builtin_amdgcn_mfma_f32_16x16x32_bf16(a, bv, acc[ct], 0, 0, 0);
        }
    }

    float b3v = b3[0];
    #pragma unroll
    for (int j = 0; j < 4; j++) {
        int rloc = w * 16 + lg * 4 + j;   // row within batch (0..63)
        float v[9];
        float mx = -1e30f;
        #pragma unroll
        for (int ct = 0; ct < 9; ct++) {
            int col = ct * 16 + lr;
            if (col < 129) { float x = acc[ct][j] + b2[col]; v[ct] = x; mx = fmaxf(mx, x); }
            else v[ct] = -1e30f;
        }
        #pragma unroll
        for (int o = 1; o < 16; o <<= 1) mx = fmaxf(mx, __shfl_xor(mx, o));
        float sum = 0.f;
        #pragma unroll
        for (int ct = 0; ct < 9; ct++) {
            int col = ct * 16 + lr;
            if (col < 129) { float e = expf(v[ct] - mx); v[ct] = e; sum += e; }
        }
        #pragma unroll
        for (int o = 1; o < 16; o <<= 1) sum += __shfl_xor(sum, o);
        float inv = 1.0f / sum;
        #pragma unroll
        for (int ct = 0; ct < 9; ct++) {
            int col = ct * 16 + lr;
            int cc = col - 64 + rloc;
            if (col < 129 && cc >= 0 && cc < 64)
                jwT_s[cc][rloc] = v[ct] * inv;   // transposed band write
        }
        if (lr == 1) {  // col 129 = p0 logit
            float pv = acc[8][j] + b3v;
            p0_s[rloc] = 1.0f / (1.0f + expf(-pv));
        }
    }
    __syncthreads();
    if (tid >= 64) return;

    // ---- phase 2: recurrence, wave 0 only (EXACT R19 loop) ----
    const int c = tid;
    f32x4 B0  = *(const f32x4*)&jwT_s[c][0];
    f32x4 B1  = *(const f32x4*)&jwT_s[c][4];
    f32x4 B2  = *(const f32x4*)&jwT_s[c][8];
    f32x4 B3  = *(const f32x4*)&jwT_s[c][12];
    f32x4 B4  = *(const f32x4*)&jwT_s[c][16];
    f32x4 B5  = *(const f32x4*)&jwT_s[c][20];
    f32x4 B6  = *(const f32x4*)&jwT_s[c][24];
    f32x4 B7  = *(const f32x4*)&jwT_s[c][28];
    f32x4 B8  = *(const f32x4*)&jwT_s[c][32];
    f32x4 B9  = *(const f32x4*)&jwT_s[c][36];
    f32x4 B10 = *(const f32x4*)&jwT_s[c][40];
    f32x4 B11 = *(const f32x4*)&jwT_s[c][44];
    f32x4 B12 = *(const f32x4*)&jwT_s[c][48];
    f32x4 B13 = *(const f32x4*)&jwT_s[c][52];
    f32x4 B14 = *(const f32x4*)&jwT_s[c][56];
    f32x4 B15 = *(const f32x4*)&jwT_s[c][60];

    const float p0r = p0_s[c];
    const int idx = slen[b] - 1;

    float ut = em_s[c][0] + em_s[c + 64][0];   // raw state
    int Eacc = 0;

    unsigned rbase = (unsigned)(uintptr_t)(__attribute__((address_space(3))) void*)&a_bc4[0];
    unsigned waddr = rbase + (unsigned)c * 4u;

    float em_lo = em_s[c][1];       // prefetched for i=1
    float em_hi = em_s[c + 64][1];

    #pragma unroll 1
    for (int i = 1; i <= idx; ++i) {
        f32x4 A0,A1,A2,A3,A4,A5,A6,A7,A8,A9,A10,A11,A12,A13,A14,A15;
        asm volatile(
            "ds_write_b32 %17, %16\n\t"
            "ds_read_b128 %0, %18 offset:0\n\t"
            "ds_read_b128 %1, %18 offset:16\n\t"
            "ds_read_b128 %2, %18 offset:32\n\t"
            "ds_read_b128 %3, %18 offset:48\n\t"
            "ds_read_b128 %4, %18 offset:64\n\t"
            "ds_read_b128 %5, %18 offset:80\n\t"
            "ds_read_b128 %6, %18 offset:96\n\t"
            "ds_read_b128 %7, %18 offset:112\n\t"
            "ds_read_b128 %8, %18 offset:128\n\t"
            "ds_read_b128 %9, %18 offset:144\n\t"
            "ds_read_b128 %10, %18 offset:160\n\t"
            "ds_read_b128 %11, %18 offset:176\n\t"
            "ds_read_b128 %12, %18 offset:192\n\t"
            "ds_read_b128 %13, %18 offset:208\n\t"
            "ds_read_b128 %14, %18 offset:224\n\t"
            "ds_read_b128 %15, %18 offset:240"
            : "=&v"(A0), "=&v"(A1), "=&v"(A2),  "=&v"(A3),
              "=&v"(A4), "=&v"(A5), "=&v"(A6),  "=&v"(A7),
              "=&v"(A8), "=&v"(A9), "=&v"(A10), "=&v"(A11),
              "=&v"(A12),"=&v"(A13),"=&v"(A14), "=&v"(A15)
            : "v"(ut), "v"(waddr), "v"(rbase)
            : "memory");
        int bits = __builtin_amdgcn_readfirstlane(__float_as_int(ut));
        int ef = (bits >> 23) & 255;
        Eacc += ef - 127;
        float scale = __int_as_float((254 - ef) << 23);   // 2^(127-ef), exact
        float emlo_eff = em_lo * scale;
        float emhi_eff = em_hi * p0r * scale;
        asm volatile("s_waitcnt lgkmcnt(0)" ::: "memory");
        __builtin_amdgcn_sched_barrier(0);
        f32x4 va = A0 * B0;
        f32x4 vb = A1 * B1;
        f32x4 vc = A2 * B2;
        f32x4 vd = A3 * B3;
        va = va + A4 * B4;   vb = vb + A5 * B5;
        vc = vc + A6 * B6;   vd = vd + A7 * B7;
        va = va + A8 * B8;   vb = vb + A9 * B9;
        vc = vc + A10 * B10; vd = vd + A11 * B11;
        va = va + A12 * B12; vb = vb + A13 * B13;
        vc = vc + A14 * B14; vd = vd + A15 * B15;
        f32x4 vs = (va + vb) + (vc + vd);
        float sum = (vs[0] + vs[1]) + (vs[2] + vs[3]);
        ut = sum * emlo_eff + ut * emhi_eff;   // raw_i
        em_lo = em_s[c][i + 1];
        em_hi = em_s[c + 64][i + 1];
    }
    float r = ut;
    #pragma unroll
    for (int o = 1; o < 64; o <<= 1) r += __shfl_xor(r, o);
    if (c == 0) {
        float res = 1.0f;
        if (idx > 0)
            res = 1.0f + 0.6931471805599453f * ((float)Eacc + __log2f(r) + 7.0f * (float)idx);
        out[b] = res;
    }
}

extern "C" void kernel_launch(void* const* d_in, const int* in_sizes, int n_in,
                              void* d_out, int out_size, void* d_ws, size_t ws_size,
                              hipStream_t stream)
{
    const float* Y   = (const float*)d_in[0];
    const float* em  = (const float*)d_in[1];
    const int*   sl  = (const int*)d_in[2];
    const float* W1  = (const float*)d_in[3];
    const float* b1  = (const float*)d_in[4];
    const float* W2  = (const float*)d_in[5];
    const float* b2  = (const float*)d_in[6];
    const float* W3  = (const float*)d_in[7];
    const float* b3  = (const float*)d_in[8];
    float* out = (float*)d_out;
    char* ws = (char*)d_ws;

    __bf16* W1T  = (__bf16*)(ws + OFF_W1T);
    __bf16* W23B = (__bf16*)(ws + OFF_W23B);
    u16*    ts   = (u16*)(ws + OFF_TS);

    prep_kernel<<<164, 256, 0, stream>>>(W1, W2, W3, W1T, W23B);
    gemm1_kernel<<<512, 256, 0, stream>>>(Y, W1T, b1, ts);
    band_recur_kernel<<<128, 256, 0, stream>>>(ts, (const u16*)W23B, b2, b3, em, sl, out);
}

// Round 21
// 71.696 us; speedup vs baseline: 1.5626x; 1.0091x over previous
//
#include <hip/hip_runtime.h>
#include <hip/hip_bf16.h>

typedef float f32x4 __attribute__((ext_vector_type(4)));
typedef __bf16 bf16x8 __attribute__((ext_vector_type(8)));
typedef unsigned short u16;

// Problem dims (fixed): B=128, T=64, H=1024, Hu=512, J=129, N=128, I=64, MJW=64
// ws layout
#define OFF_W1T  0u            // 512x1024 bf16 = 1048576 B  (W1T[n][k] = W1[k][n])
#define OFF_W23B 1048576u      // 144x512 bf16 fragment-order = 147456 B
#define OFF_TS   1196032u      // 8192x512 bf16 = 8388608 B

static __device__ __forceinline__ u16 f2bf(float x) {
    __bf16 h = (__bf16)x;
    return __builtin_bit_cast(u16, h);
}

__device__ __forceinline__ void gload16(const void* g, void* l) {
    __builtin_amdgcn_global_load_lds(
        (const __attribute__((address_space(1))) void*)g,
        (__attribute__((address_space(3))) void*)l,
        16, 0, 0);
}

// ---------------------------------------------------------------------------
// prep (unchanged)
// ---------------------------------------------------------------------------
__global__ __launch_bounds__(256) void prep_kernel(
    const float* __restrict__ W1, const float* __restrict__ W2,
    const float* __restrict__ W3,
    __bf16* __restrict__ W1T, __bf16* __restrict__ W23B)
{
    const int t = threadIdx.x;
    if (blockIdx.x < 128) {
        __shared__ __bf16 lds_t[64][72];
        const int kt = blockIdx.x >> 3, nt = blockIdx.x & 7;
        const int k0 = kt * 64, n0 = nt * 64;
        {
            const int kr = t >> 2, c0 = (t & 3) * 16;
            const float* src = W1 + (size_t)(k0 + kr) * 512 + n0 + c0;
            #pragma unroll
            for (int q = 0; q < 4; ++q) {
                float4 v = *(const float4*)(src + q * 4);
                lds_t[kr][c0 + q * 4 + 0] = (__bf16)v.x;
                lds_t[kr][c0 + q * 4 + 1] = (__bf16)v.y;
                lds_t[kr][c0 + q * 4 + 2] = (__bf16)v.z;
                lds_t[kr][c0 + q * 4 + 3] = (__bf16)v.w;
            }
        }
        __syncthreads();
        {
            const int nr = t >> 2, kc = (t & 3) * 16;
            bf16x8 o0, o1;
            #pragma unroll
            for (int j = 0; j < 8; ++j) o0[j] = lds_t[kc + j][nr];
            #pragma unroll
            for (int j = 0; j < 8; ++j) o1[j] = lds_t[kc + 8 + j][nr];
            __bf16* dst = W1T + (size_t)(n0 + nr) * 1024 + k0 + kc;
            *(bf16x8*)(dst)     = o0;
            *(bf16x8*)(dst + 8) = o1;
        }
    } else {
        int g = (blockIdx.x - 128) * 256 + t;   // 0..9215
        if (g < 9216) {
            int n = g >> 6;            // 0..143
            int k8 = (g & 63) * 8;     // 0,8,..,504
            bf16x8 v;
            #pragma unroll
            for (int j = 0; j < 8; ++j) {
                int k = k8 + j;
                float x = 0.0f;
                if (n < 129) x = W2[(size_t)k * 129 + n];
                else if (n == 129) x = W3[k];
                v[j] = (__bf16)x;
            }
            int kk = k8 >> 5, lg = (k8 >> 3) & 3, ct = n >> 4, lr = n & 15;
            *(bf16x8*)&W23B[(((size_t)(kk * 9 + ct)) * 64 + lg * 16 + lr) * 8] = v;
        }
    }
}

// ---------------------------------------------------------------------------
// GEMM1 (unchanged from R19/R20: ring-3, 3 blocks/CU, stage-dist-2, vmcnt(4),
// 1 barrier/step, XCD-chunk swizzle, T21 both-sides swizzles; ~22us)
// ---------------------------------------------------------------------------
__global__ __launch_bounds__(256, 3) void gemm1_kernel(
    const float* __restrict__ Y, const __bf16* __restrict__ W1T,
    const float* __restrict__ b1, u16* __restrict__ ts)
{
    __shared__ float  As[3][64 * 32];
    __shared__ __bf16 Bs[3][128 * 32];
    const int tid = threadIdx.x;
    const int bid = blockIdx.x;
    const int half = bid >> 8;
    const int b8 = bid & 255;
    const int xcd = b8 & 7;
    const int ii = b8 >> 3;
    const int rb = half * 64 + xcd * 8 + (ii >> 2);
    const int tb = ii & 3;
    const int m0 = rb * 64, n0 = tb * 128;
    const int wid = tid >> 6, lane = tid & 63;
    const int wr = wid >> 1, wc = wid & 1;
    const int lr = lane & 15, lg = lane >> 4;
    const int al = lane >> 3;
    const int au = (lane & 7) ^ al;
    const float* yA0 = Y + (size_t)(m0 + (wid * 2 + 0) * 8 + al) * 1024 + au * 4;
    const float* yA1 = Y + (size_t)(m0 + (wid * 2 + 1) * 8 + al) * 1024 + au * 4;
    const int bl = lane >> 2;
    const int bu = (lane & 3) ^ ((bl >> 1) & 3);
    const __bf16* wB0 = W1T + (size_t)(n0 + (wid * 2 + 0) * 16 + bl) * 1024 + bu * 8;
    const __bf16* wB1 = W1T + (size_t)(n0 + (wid * 2 + 1) * 16 + bl) * 1024 + bu * 8;

    f32x4 acc[2][4];
    #pragma unroll
    for (int m = 0; m < 2; m++)
        #pragma unroll
        for (int n = 0; n < 4; n++) { f32x4 z = {0.f,0.f,0.f,0.f}; acc[m][n] = z; }

#define STAGE(buf, kt) do { \
    gload16(yA0 + (kt) * 32, &As[buf][(wid * 2 + 0) * 256]); \
    gload16(yA1 + (kt) * 32, &As[buf][(wid * 2 + 1) * 256]); \
    gload16(wB0 + (kt) * 32, &Bs[buf][(wid * 2 + 0) * 512]); \
    gload16(wB1 + (kt) * 32, &Bs[buf][(wid * 2 + 1) * 512]); \
} while (0)

#define COMPUTE(buf) do { \
    bf16x8 af[2]; bf16x8 bfr[4]; \
    _Pragma("unroll") \
    for (int m = 0; m < 2; ++m) { \
        const int row = wr * 32 + m * 16 + lr; \
        const int r7 = row & 7; \
        float4 h0 = *(const float4*)&As[buf][row * 32 + (((lg * 2 + 0) ^ r7) * 4)]; \
        float4 h1 = *(const float4*)&As[buf][row * 32 + (((lg * 2 + 1) ^ r7) * 4)]; \
        bf16x8 tt; \
        tt[0]=(__bf16)h0.x; tt[1]=(__bf16)h0.y; tt[2]=(__bf16)h0.z; tt[3]=(__bf16)h0.w; \
        tt[4]=(__bf16)h1.x; tt[5]=(__bf16)h1.y; tt[6]=(__bf16)h1.z; tt[7]=(__bf16)h1.w; \
        af[m] = tt; \
    } \
    _Pragma("unroll") \
    for (int n = 0; n < 4; ++n) { \
        const int rowb = wc * 64 + n * 16 + lr; \
        bfr[n] = *(const bf16x8*)&Bs[buf][rowb * 32 + ((lg ^ ((rowb >> 1) & 3)) * 8)]; \
    } \
    __builtin_amdgcn_s_setprio(1); \
    _Pragma("unroll") \
    for (int m = 0; m < 2; ++m) \
        _Pragma("unroll") \
        for (int n = 0; n < 4; ++n) \
            acc[m][n] = __builtin_amdgcn_mfma_f32_16x16x32_bf16(af[m], bfr[n], acc[m][n], 0, 0, 0); \
    __builtin_amdgcn_s_setprio(0); \
} while (0)

    STAGE(0, 0); STAGE(1, 1);
    {
        int buf = 0, sbuf = 2;
        #pragma unroll 1
        for (int kt = 0; kt < 30; ++kt) {
            asm volatile("s_waitcnt vmcnt(4)" ::: "memory");
            __builtin_amdgcn_s_barrier();
            COMPUTE(buf);
            STAGE(sbuf, kt + 2);
            buf  = (buf  == 2) ? 0 : buf  + 1;
            sbuf = (sbuf == 2) ? 0 : sbuf + 1;
        }
    }
    asm volatile("s_waitcnt vmcnt(4)" ::: "memory");
    __builtin_amdgcn_s_barrier();
    COMPUTE(0);
    asm volatile("s_waitcnt vmcnt(0)" ::: "memory");
    __builtin_amdgcn_s_barrier();
    COMPUTE(1);

    #pragma unroll
    for (int m = 0; m < 2; m++) {
        #pragma unroll
        for (int n = 0; n < 4; n++) {
            int col = n0 + wc * 64 + n * 16 + lr;
            float bias = b1[col];
            #pragma unroll
            for (int j = 0; j < 4; j++) {
                int row = m0 + wr * 32 + m * 16 + lg * 4 + j;
                float v = tanhf(acc[m][n][j] + bias);
                ts[(size_t)row * 512 + col] = f2bf(v);
            }
        }
    }
#undef STAGE
#undef COMPUTE
}

// ---------------------------------------------------------------------------
// FUSED band + recur (R20 structure) + B-register keepalive:
// an empty asm with "+v"(B0..B15) at the top of the loop forces the 64-VGPR
// band to stay RESIDENT (R20's VGPR_Count=92 proved it was spilled/reloaded
// behind the "memory"-clobbered cluster). Verification signal: VGPR >= 150.
// ---------------------------------------------------------------------------
__global__ __launch_bounds__(256, 1) void band_recur_kernel(
    const u16* __restrict__ ts, const u16* __restrict__ W23B,
    const float* __restrict__ b2, const float* __restrict__ b3,
    const float* __restrict__ em, const int* __restrict__ slen,
    float* __restrict__ out)
{
    __shared__ float jwT_s[64][65];   // [c][k] = M[k][c] (pre-shifted transposed band)
    __shared__ float em_s[128][65];
    __shared__ float p0_s[64];
    __shared__ f32x4 a_bc4[16];
    const int b = blockIdx.x;
    const int tid = threadIdx.x;
    const int w = tid >> 6, lane = tid & 63;
    const int lr = lane & 15, lg = lane >> 4;
    const int r0 = b * 64 + w * 16;

    // stage emission (independent of the GEMM; overlaps it)
    {
        const float4* eg = (const float4*)(em + (size_t)b * 8192);
        #pragma unroll
        for (int q = 0; q < 8; ++q) {
            int i4 = tid + q * 256;
            float4 v = eg[i4];
            int base = i4 * 4; int n = base >> 6; int ii = base & 63;
            em_s[n][ii] = v.x; em_s[n][ii + 1] = v.y; em_s[n][ii + 2] = v.z; em_s[n][ii + 3] = v.w;
        }
    }

    f32x4 acc[9];
    #pragma unroll
    for (int ct = 0; ct < 9; ct++) { f32x4 z = {0.f,0.f,0.f,0.f}; acc[ct] = z; }

    #pragma unroll 4
    for (int kk = 0; kk < 16; ++kk) {
        bf16x8 a = *(const bf16x8*)(ts + (size_t)(r0 + lr) * 512 + kk * 32 + lg * 8);
        #pragma unroll
        for (int ct = 0; ct < 9; ct++) {
            bf16x8 bv = *(const bf16x8*)(W23B + ((size_t)(kk * 9 + ct) * 64 + lane) * 8);
            acc[ct] = __builtin_amdgcn_mfma_f32_16x16x32_bf16(a, bv, acc[ct], 0, 0, 0);
        }
    }

    float b3v = b3[0];
    #pragma unroll
    for (int j = 0; j < 4; j++) {
        int rloc = w * 16 + lg * 4 + j;   // row within batch (0..63)
        float v[9];
        float mx = -1e30f;
        #pragma unroll
        for (int ct = 0; ct < 9; ct++) {
            int col = ct * 16 + lr;
            if (col < 129) { float x = acc[ct][j] + b2[col]; v[ct] = x; mx = fmaxf(mx, x); }
            else v[ct] = -1e30f;
        }
        #pragma unroll
        for (int o = 1; o < 16; o <<= 1) mx = fmaxf(mx, __shfl_xor(mx, o));
        float sum = 0.f;
        #pragma unroll
        for (int ct = 0; ct < 9; ct++) {
            int col = ct * 16 + lr;
            if (col < 129) { float e = expf(v[ct] - mx); v[ct] = e; sum += e; }
        }
        #pragma unroll
        for (int o = 1; o < 16; o <<= 1) sum += __shfl_xor(sum, o);
        float inv = 1.0f / sum;
        #pragma unroll
        for (int ct = 0; ct < 9; ct++) {
            int col = ct * 16 + lr;
            int cc = col - 64 + rloc;
            if (col < 129 && cc >= 0 && cc < 64)
                jwT_s[cc][rloc] = v[ct] * inv;   // transposed band write
        }
        if (lr == 1) {  // col 129 = p0 logit
            float pv = acc[8][j] + b3v;
            p0_s[rloc] = 1.0f / (1.0f + expf(-pv));
        }
    }
    __syncthreads();
    if (tid >= 64) return;

    // ---- phase 2: recurrence, wave 0 only ----
    const int c = tid;
    f32x4 B0  = *(const f32x4*)&jwT_s[c][0];
    f32x4 B1  = *(const f32x4*)&jwT_s[c][4];
    f32x4 B2  = *(const f32x4*)&jwT_s[c][8];
    f32x4 B3  = *(const f32x4*)&jwT_s[c][12];
    f32x4 B4  = *(const f32x4*)&jwT_s[c][16];
    f32x4 B5  = *(const f32x4*)&jwT_s[c][20];
    f32x4 B6  = *(const f32x4*)&jwT_s[c][24];
    f32x4 B7  = *(const f32x4*)&jwT_s[c][28];
    f32x4 B8  = *(const f32x4*)&jwT_s[c][32];
    f32x4 B9  = *(const f32x4*)&jwT_s[c][36];
    f32x4 B10 = *(const f32x4*)&jwT_s[c][40];
    f32x4 B11 = *(const f32x4*)&jwT_s[c][44];
    f32x4 B12 = *(const f32x4*)&jwT_s[c][48];
    f32x4 B13 = *(const f32x4*)&jwT_s[c][52];
    f32x4 B14 = *(const f32x4*)&jwT_s[c][56];
    f32x4 B15 = *(const f32x4*)&jwT_s[c][60];

    const float p0r = p0_s[c];
    const int idx = slen[b] - 1;

    float ut = em_s[c][0] + em_s[c + 64][0];   // raw state
    int Eacc = 0;

    unsigned rbase = (unsigned)(uintptr_t)(__attribute__((address_space(3))) void*)&a_bc4[0];
    unsigned waddr = rbase + (unsigned)c * 4u;

    float em_lo = em_s[c][1];       // prefetched for i=1
    float em_hi = em_s[c + 64][1];

    #pragma unroll 1
    for (int i = 1; i <= idx; ++i) {
        // keepalive: force the 64-VGPR band resident across the clobbered asm
        asm volatile("" : "+v"(B0), "+v"(B1), "+v"(B2),  "+v"(B3),
                          "+v"(B4), "+v"(B5), "+v"(B6),  "+v"(B7),
                          "+v"(B8), "+v"(B9), "+v"(B10), "+v"(B11),
                          "+v"(B12),"+v"(B13),"+v"(B14), "+v"(B15));
        f32x4 A0,A1,A2,A3,A4,A5,A6,A7,A8,A9,A10,A11,A12,A13,A14,A15;
        asm volatile(
            "ds_write_b32 %17, %16\n\t"
            "ds_read_b128 %0, %18 offset:0\n\t"
            "ds_read_b128 %1, %18 offset:16\n\t"
            "ds_read_b128 %2, %18 offset:32\n\t"
            "ds_read_b128 %3, %18 offset:48\n\t"
            "ds_read_b128 %4, %18 offset:64\n\t"
            "ds_read_b128 %5, %18 offset:80\n\t"
            "ds_read_b128 %6, %18 offset:96\n\t"
            "ds_read_b128 %7, %18 offset:112\n\t"
            "ds_read_b128 %8, %18 offset:128\n\t"
            "ds_read_b128 %9, %18 offset:144\n\t"
            "ds_read_b128 %10, %18 offset:160\n\t"
            "ds_read_b128 %11, %18 offset:176\n\t"
            "ds_read_b128 %12, %18 offset:192\n\t"
            "ds_read_b128 %13, %18 offset:208\n\t"
            "ds_read_b128 %14, %18 offset:224\n\t"
            "ds_read_b128 %15, %18 offset:240"
            : "=&v"(A0), "=&v"(A1), "=&v"(A2),  "=&v"(A3),
              "=&v"(A4), "=&v"(A5), "=&v"(A6),  "=&v"(A7),
              "=&v"(A8), "=&v"(A9), "=&v"(A10), "=&v"(A11),
              "=&v"(A12),"=&v"(A13),"=&v"(A14), "=&v"(A15)
            : "v"(ut), "v"(waddr), "v"(rbase)
            : "memory");
        int bits = __builtin_amdgcn_readfirstlane(__float_as_int(ut));
        int ef = (bits >> 23) & 255;
        Eacc += ef - 127;
        float scale = __int_as_float((254 - ef) << 23);   // 2^(127-ef), exact
        float emlo_eff = em_lo * scale;
        float emhi_eff = em_hi * p0r * scale;
        asm volatile("s_waitcnt lgkmcnt(0)" ::: "memory");
        __builtin_amdgcn_sched_barrier(0);
        f32x4 va = A0 * B0;
        f32x4 vb = A1 * B1;
        f32x4 vc = A2 * B2;
        f32x4 vd = A3 * B3;
        va = va + A4 * B4;   vb = vb + A5 * B5;
        vc = vc + A6 * B6;   vd = vd + A7 * B7;
        va = va + A8 * B8;   vb = vb + A9 * B9;
        vc = vc + A10 * B10; vd = vd + A11 * B11;
        va = va + A12 * B12; vb = vb + A13 * B13;
        vc = vc + A14 * B14; vd = vd + A15 * B15;
        f32x4 vs = (va + vb) + (vc + vd);
        float sum = (vs[0] + vs[1]) + (vs[2] + vs[3]);
        ut = sum * emlo_eff + ut * emhi_eff;   // raw_i
        em_lo = em_s[c][i + 1];
        em_hi = em_s[c + 64][i + 1];
    }
    float r = ut;
    #pragma unroll
    for (int o = 1; o < 64; o <<= 1) r += __shfl_xor(r, o);
    if (c == 0) {
        float res = 1.0f;
        if (idx > 0)
            res = 1.0f + 0.6931471805599453f * ((float)Eacc + __log2f(r) + 7.0f * (float)idx);
        out[b] = res;
    }
}

extern "C" void kernel_launch(void* const* d_in, const int* in_sizes, int n_in,
                              void* d_out, int out_size, void* d_ws, size_t ws_size,
                              hipStream_t stream)
{
    const float* Y   = (const float*)d_in[0];
    const float* em  = (const float*)d_in[1];
    const int*   sl  = (const int*)d_in[2];
    const float* W1  = (const float*)d_in[3];
    const float* b1  = (const float*)d_in[4];
    const float* W2  = (const float*)d_in[5];
    const float* b2  = (const float*)d_in[6];
    const float* W3  = (const float*)d_in[7];
    const float* b3  = (const float*)d_in[8];
    float* out = (float*)d_out;
    char* ws = (char*)d_ws;

    __bf16* W1T  = (__bf16*)(ws + OFF_W1T);
    __bf16* W23B = (__bf16*)(ws + OFF_W23B);
    u16*    ts   = (u16*)(ws + OFF_TS);

    prep_kernel<<<164, 256, 0, stream>>>(W1, W2, W3, W1T, W23B);
    gemm1_kernel<<<512, 256, 0, stream>>>(Y, W1T, b1, ts);
    band_recur_kernel<<<128, 256, 0, stream>>>(ts, (const u16*)W23B, b2, b3, em, sl, out);
}

// Round 22
// 71.275 us; speedup vs baseline: 1.5719x; 1.0059x over previous
//
#include <hip/hip_runtime.h>
#include <hip/hip_bf16.h>

typedef float f32x4 __attribute__((ext_vector_type(4)));
typedef __bf16 bf16x8 __attribute__((ext_vector_type(8)));
typedef unsigned short u16;

// Problem dims (fixed): B=128, T=64, H=1024, Hu=512, J=129, N=128, I=64, MJW=64
// ws layout
#define OFF_W1T  0u            // 512x1024 bf16 = 1048576 B  (W1T[n][k] = W1[k][n])
#define OFF_W23B 1048576u      // 144x512 bf16 fragment-order = 147456 B
#define OFF_TS   1196032u      // 8192x512 bf16 = 8388608 B

static __device__ __forceinline__ u16 f2bf(float x) {
    __bf16 h = (__bf16)x;
    return __builtin_bit_cast(u16, h);
}

__device__ __forceinline__ void gload16(const void* g, void* l) {
    __builtin_amdgcn_global_load_lds(
        (const __attribute__((address_space(1))) void*)g,
        (__attribute__((address_space(3))) void*)l,
        16, 0, 0);
}

// ---------------------------------------------------------------------------
// prep (unchanged)
// ---------------------------------------------------------------------------
__global__ __launch_bounds__(256) void prep_kernel(
    const float* __restrict__ W1, const float* __restrict__ W2,
    const float* __restrict__ W3,
    __bf16* __restrict__ W1T, __bf16* __restrict__ W23B)
{
    const int t = threadIdx.x;
    if (blockIdx.x < 128) {
        __shared__ __bf16 lds_t[64][72];
        const int kt = blockIdx.x >> 3, nt = blockIdx.x & 7;
        const int k0 = kt * 64, n0 = nt * 64;
        {
            const int kr = t >> 2, c0 = (t & 3) * 16;
            const float* src = W1 + (size_t)(k0 + kr) * 512 + n0 + c0;
            #pragma unroll
            for (int q = 0; q < 4; ++q) {
                float4 v = *(const float4*)(src + q * 4);
                lds_t[kr][c0 + q * 4 + 0] = (__bf16)v.x;
                lds_t[kr][c0 + q * 4 + 1] = (__bf16)v.y;
                lds_t[kr][c0 + q * 4 + 2] = (__bf16)v.z;
                lds_t[kr][c0 + q * 4 + 3] = (__bf16)v.w;
            }
        }
        __syncthreads();
        {
            const int nr = t >> 2, kc = (t & 3) * 16;
            bf16x8 o0, o1;
            #pragma unroll
            for (int j = 0; j < 8; ++j) o0[j] = lds_t[kc + j][nr];
            #pragma unroll
            for (int j = 0; j < 8; ++j) o1[j] = lds_t[kc + 8 + j][nr];
            __bf16* dst = W1T + (size_t)(n0 + nr) * 1024 + k0 + kc;
            *(bf16x8*)(dst)     = o0;
            *(bf16x8*)(dst + 8) = o1;
        }
    } else {
        int g = (blockIdx.x - 128) * 256 + t;   // 0..9215
        if (g < 9216) {
            int n = g >> 6;            // 0..143
            int k8 = (g & 63) * 8;     // 0,8,..,504
            bf16x8 v;
            #pragma unroll
            for (int j = 0; j < 8; ++j) {
                int k = k8 + j;
                float x = 0.0f;
                if (n < 129) x = W2[(size_t)k * 129 + n];
                else if (n == 129) x = W3[k];
                v[j] = (__bf16)x;
            }
            int kk = k8 >> 5, lg = (k8 >> 3) & 3, ct = n >> 4, lr = n & 15;
            *(bf16x8*)&W23B[(((size_t)(kk * 9 + ct)) * 64 + lg * 16 + lr) * 8] = v;
        }
    }
}

// ---------------------------------------------------------------------------
// GEMM1 (unchanged from R19-R21: ring-3, 3 blocks/CU, stage-dist-2, vmcnt(4),
// 1 barrier/step, XCD-chunk swizzle, T21 both-sides swizzles; ~22us)
// ---------------------------------------------------------------------------
__global__ __launch_bounds__(256, 3) void gemm1_kernel(
    const float* __restrict__ Y, const __bf16* __restrict__ W1T,
    const float* __restrict__ b1, u16* __restrict__ ts)
{
    __shared__ float  As[3][64 * 32];
    __shared__ __bf16 Bs[3][128 * 32];
    const int tid = threadIdx.x;
    const int bid = blockIdx.x;
    const int half = bid >> 8;
    const int b8 = bid & 255;
    const int xcd = b8 & 7;
    const int ii = b8 >> 3;
    const int rb = half * 64 + xcd * 8 + (ii >> 2);
    const int tb = ii & 3;
    const int m0 = rb * 64, n0 = tb * 128;
    const int wid = tid >> 6, lane = tid & 63;
    const int wr = wid >> 1, wc = wid & 1;
    const int lr = lane & 15, lg = lane >> 4;
    const int al = lane >> 3;
    const int au = (lane & 7) ^ al;
    const float* yA0 = Y + (size_t)(m0 + (wid * 2 + 0) * 8 + al) * 1024 + au * 4;
    const float* yA1 = Y + (size_t)(m0 + (wid * 2 + 1) * 8 + al) * 1024 + au * 4;
    const int bl = lane >> 2;
    const int bu = (lane & 3) ^ ((bl >> 1) & 3);
    const __bf16* wB0 = W1T + (size_t)(n0 + (wid * 2 + 0) * 16 + bl) * 1024 + bu * 8;
    const __bf16* wB1 = W1T + (size_t)(n0 + (wid * 2 + 1) * 16 + bl) * 1024 + bu * 8;

    f32x4 acc[2][4];
    #pragma unroll
    for (int m = 0; m < 2; m++)
        #pragma unroll
        for (int n = 0; n < 4; n++) { f32x4 z = {0.f,0.f,0.f,0.f}; acc[m][n] = z; }

#define STAGE(buf, kt) do { \
    gload16(yA0 + (kt) * 32, &As[buf][(wid * 2 + 0) * 256]); \
    gload16(yA1 + (kt) * 32, &As[buf][(wid * 2 + 1) * 256]); \
    gload16(wB0 + (kt) * 32, &Bs[buf][(wid * 2 + 0) * 512]); \
    gload16(wB1 + (kt) * 32, &Bs[buf][(wid * 2 + 1) * 512]); \
} while (0)

#define COMPUTE(buf) do { \
    bf16x8 af[2]; bf16x8 bfr[4]; \
    _Pragma("unroll") \
    for (int m = 0; m < 2; ++m) { \
        const int row = wr * 32 + m * 16 + lr; \
        const int r7 = row & 7; \
        float4 h0 = *(const float4*)&As[buf][row * 32 + (((lg * 2 + 0) ^ r7) * 4)]; \
        float4 h1 = *(const float4*)&As[buf][row * 32 + (((lg * 2 + 1) ^ r7) * 4)]; \
        bf16x8 tt; \
        tt[0]=(__bf16)h0.x; tt[1]=(__bf16)h0.y; tt[2]=(__bf16)h0.z; tt[3]=(__bf16)h0.w; \
        tt[4]=(__bf16)h1.x; tt[5]=(__bf16)h1.y; tt[6]=(__bf16)h1.z; tt[7]=(__bf16)h1.w; \
        af[m] = tt; \
    } \
    _Pragma("unroll") \
    for (int n = 0; n < 4; ++n) { \
        const int rowb = wc * 64 + n * 16 + lr; \
        bfr[n] = *(const bf16x8*)&Bs[buf][rowb * 32 + ((lg ^ ((rowb >> 1) & 3)) * 8)]; \
    } \
    __builtin_amdgcn_s_setprio(1); \
    _Pragma("unroll") \
    for (int m = 0; m < 2; ++m) \
        _Pragma("unroll") \
        for (int n = 0; n < 4; ++n) \
            acc[m][n] = __builtin_amdgcn_mfma_f32_16x16x32_bf16(af[m], bfr[n], acc[m][n], 0, 0, 0); \
    __builtin_amdgcn_s_setprio(0); \
} while (0)

    STAGE(0, 0); STAGE(1, 1);
    {
        int buf = 0, sbuf = 2;
        #pragma unroll 1
        for (int kt = 0; kt < 30; ++kt) {
            asm volatile("s_waitcnt vmcnt(4)" ::: "memory");
            __builtin_amdgcn_s_barrier();
            COMPUTE(buf);
            STAGE(sbuf, kt + 2);
            buf  = (buf  == 2) ? 0 : buf  + 1;
            sbuf = (sbuf == 2) ? 0 : sbuf + 1;
        }
    }
    asm volatile("s_waitcnt vmcnt(4)" ::: "memory");
    __builtin_amdgcn_s_barrier();
    COMPUTE(0);
    asm volatile("s_waitcnt vmcnt(0)" ::: "memory");
    __builtin_amdgcn_s_barrier();
    COMPUTE(1);

    #pragma unroll
    for (int m = 0; m < 2; m++) {
        #pragma unroll
        for (int n = 0; n < 4; n++) {
            int col = n0 + wc * 64 + n * 16 + lr;
            float bias = b1[col];
            #pragma unroll
            for (int j = 0; j < 4; j++) {
                int row = m0 + wr * 32 + m * 16 + lg * 4 + j;
                float v = tanhf(acc[m][n][j] + bias);
                ts[(size_t)row * 512 + col] = f2bf(v);
            }
        }
    }
#undef STAGE
#undef COMPUTE
}

// ---------------------------------------------------------------------------
// FUSED band + recur (R20 structure). Recur loop now uses COUNTED lgkmcnt
// waits (12/8/4/0) interleaved with FMA groups so VALU overlaps the in-order
// DS completion tail instead of draining it (was a single lgkmcnt(0)).
// Each wait is followed by sched_barrier(0) (rule 18).
// ---------------------------------------------------------------------------
__global__ __launch_bounds__(256, 1) void band_recur_kernel(
    const u16* __restrict__ ts, const u16* __restrict__ W23B,
    const float* __restrict__ b2, const float* __restrict__ b3,
    const float* __restrict__ em, const int* __restrict__ slen,
    float* __restrict__ out)
{
    __shared__ float jwT_s[64][65];   // [c][k] = M[k][c] (pre-shifted transposed band)
    __shared__ float em_s[128][65];
    __shared__ float p0_s[64];
    __shared__ f32x4 a_bc4[16];
    const int b = blockIdx.x;
    const int tid = threadIdx.x;
    const int w = tid >> 6, lane = tid & 63;
    const int lr = lane & 15, lg = lane >> 4;
    const int r0 = b * 64 + w * 16;

    // stage emission (independent of the GEMM; overlaps it)
    {
        const float4* eg = (const float4*)(em + (size_t)b * 8192);
        #pragma unroll
        for (int q = 0; q < 8; ++q) {
            int i4 = tid + q * 256;
            float4 v = eg[i4];
            int base = i4 * 4; int n = base >> 6; int ii = base & 63;
            em_s[n][ii] = v.x; em_s[n][ii + 1] = v.y; em_s[n][ii + 2] = v.z; em_s[n][ii + 3] = v.w;
        }
    }

    f32x4 acc[9];
    #pragma unroll
    for (int ct = 0; ct < 9; ct++) { f32x4 z = {0.f,0.f,0.f,0.f}; acc[ct] = z; }

    #pragma unroll 4
    for (int kk = 0; kk < 16; ++kk) {
        bf16x8 a = *(const bf16x8*)(ts + (size_t)(r0 + lr) * 512 + kk * 32 + lg * 8);
        #pragma unroll
        for (int ct = 0; ct < 9; ct++) {
            bf16x8 bv = *(const bf16x8*)(W23B + ((size_t)(kk * 9 + ct) * 64 + lane) * 8);
            acc[ct] = __builtin_amdgcn_mfma_f32_16x16x32_bf16(a, bv, acc[ct], 0, 0, 0);
        }
    }

    float b3v = b3[0];
    #pragma unroll
    for (int j = 0; j < 4; j++) {
        int rloc = w * 16 + lg * 4 + j;   // row within batch (0..63)
        float v[9];
        float mx = -1e30f;
        #pragma unroll
        for (int ct = 0; ct < 9; ct++) {
            int col = ct * 16 + lr;
            if (col < 129) { float x = acc[ct][j] + b2[col]; v[ct] = x; mx = fmaxf(mx, x); }
            else v[ct] = -1e30f;
        }
        #pragma unroll
        for (int o = 1; o < 16; o <<= 1) mx = fmaxf(mx, __shfl_xor(mx, o));
        float sum = 0.f;
        #pragma unroll
        for (int ct = 0; ct < 9; ct++) {
            int col = ct * 16 + lr;
            if (col < 129) { float e = expf(v[ct] - mx); v[ct] = e; sum += e; }
        }
        #pragma unroll
        for (int o = 1; o < 16; o <<= 1) sum += __shfl_xor(sum, o);
        float inv = 1.0f / sum;
        #pragma unroll
        for (int ct = 0; ct < 9; ct++) {
            int col = ct * 16 + lr;
            int cc = col - 64 + rloc;
            if (col < 129 && cc >= 0 && cc < 64)
                jwT_s[cc][rloc] = v[ct] * inv;   // transposed band write
        }
        if (lr == 1) {  // col 129 = p0 logit
            float pv = acc[8][j] + b3v;
            p0_s[rloc] = 1.0f / (1.0f + expf(-pv));
        }
    }
    __syncthreads();
    if (tid >= 64) return;

    // ---- phase 2: recurrence, wave 0 only ----
    const int c = tid;
    f32x4 B0  = *(const f32x4*)&jwT_s[c][0];
    f32x4 B1  = *(const f32x4*)&jwT_s[c][4];
    f32x4 B2  = *(const f32x4*)&jwT_s[c][8];
    f32x4 B3  = *(const f32x4*)&jwT_s[c][12];
    f32x4 B4  = *(const f32x4*)&jwT_s[c][16];
    f32x4 B5  = *(const f32x4*)&jwT_s[c][20];
    f32x4 B6  = *(const f32x4*)&jwT_s[c][24];
    f32x4 B7  = *(const f32x4*)&jwT_s[c][28];
    f32x4 B8  = *(const f32x4*)&jwT_s[c][32];
    f32x4 B9  = *(const f32x4*)&jwT_s[c][36];
    f32x4 B10 = *(const f32x4*)&jwT_s[c][40];
    f32x4 B11 = *(const f32x4*)&jwT_s[c][44];
    f32x4 B12 = *(const f32x4*)&jwT_s[c][48];
    f32x4 B13 = *(const f32x4*)&jwT_s[c][52];
    f32x4 B14 = *(const f32x4*)&jwT_s[c][56];
    f32x4 B15 = *(const f32x4*)&jwT_s[c][60];

    const float p0r = p0_s[c];
    const int idx = slen[b] - 1;

    float ut = em_s[c][0] + em_s[c + 64][0];   // raw state
    int Eacc = 0;

    unsigned rbase = (unsigned)(uintptr_t)(__attribute__((address_space(3))) void*)&a_bc4[0];
    unsigned waddr = rbase + (unsigned)c * 4u;

    float em_lo = em_s[c][1];       // prefetched for i=1
    float em_hi = em_s[c + 64][1];

    #pragma unroll 1
    for (int i = 1; i <= idx; ++i) {
        f32x4 A0,A1,A2,A3,A4,A5,A6,A7,A8,A9,A10,A11,A12,A13,A14,A15;
        asm volatile(
            "ds_write_b32 %17, %16\n\t"
            "ds_read_b128 %0, %18 offset:0\n\t"
            "ds_read_b128 %1, %18 offset:16\n\t"
            "ds_read_b128 %2, %18 offset:32\n\t"
            "ds_read_b128 %3, %18 offset:48\n\t"
            "ds_read_b128 %4, %18 offset:64\n\t"
            "ds_read_b128 %5, %18 offset:80\n\t"
            "ds_read_b128 %6, %18 offset:96\n\t"
            "ds_read_b128 %7, %18 offset:112\n\t"
            "ds_read_b128 %8, %18 offset:128\n\t"
            "ds_read_b128 %9, %18 offset:144\n\t"
            "ds_read_b128 %10, %18 offset:160\n\t"
            "ds_read_b128 %11, %18 offset:176\n\t"
            "ds_read_b128 %12, %18 offset:192\n\t"
            "ds_read_b128 %13, %18 offset:208\n\t"
            "ds_read_b128 %14, %18 offset:224\n\t"
            "ds_read_b128 %15, %18 offset:240"
            : "=&v"(A0), "=&v"(A1), "=&v"(A2),  "=&v"(A3),
              "=&v"(A4), "=&v"(A5), "=&v"(A6),  "=&v"(A7),
              "=&v"(A8), "=&v"(A9), "=&v"(A10), "=&v"(A11),
              "=&v"(A12),"=&v"(A13),"=&v"(A14), "=&v"(A15)
            : "v"(ut), "v"(waddr), "v"(rbase)
            : "memory");
        // flush (overlaps DS latency): scale folded into this iter's em
        int bits = __builtin_amdgcn_readfirstlane(__float_as_int(ut));
        int ef = (bits >> 23) & 255;
        Eacc += ef - 127;
        float scale = __int_as_float((254 - ef) << 23);   // 2^(127-ef), exact
        float emlo_eff = em_lo * scale;
        float emhi_eff = em_hi * p0r * scale;
        // counted-wait interleave: FMA groups overlap the DS completion tail
        f32x4 va, vb, vc, vd;
        asm volatile("s_waitcnt lgkmcnt(12)" ::: "memory");   // write+A0..A3 done
        __builtin_amdgcn_sched_barrier(0);
        va = A0 * B0;  vb = A1 * B1;  vc = A2 * B2;  vd = A3 * B3;
        asm volatile("s_waitcnt lgkmcnt(8)" ::: "memory");    // A4..A7 done
        __builtin_amdgcn_sched_barrier(0);
        va = va + A4 * B4;   vb = vb + A5 * B5;
        vc = vc + A6 * B6;   vd = vd + A7 * B7;
        asm volatile("s_waitcnt lgkmcnt(4)" ::: "memory");    // A8..A11 done
        __builtin_amdgcn_sched_barrier(0);
        va = va + A8 * B8;   vb = vb + A9 * B9;
        vc = vc + A10 * B10; vd = vd + A11 * B11;
        asm volatile("s_waitcnt lgkmcnt(0)" ::: "memory");    // A12..A15 done
        __builtin_amdgcn_sched_barrier(0);
        va = va + A12 * B12; vb = vb + A13 * B13;
        vc = vc + A14 * B14; vd = vd + A15 * B15;
        f32x4 vs = (va + vb) + (vc + vd);
        float sum = (vs[0] + vs[1]) + (vs[2] + vs[3]);
        ut = sum * emlo_eff + ut * emhi_eff;   // raw_i
        em_lo = em_s[c][i + 1];
        em_hi = em_s[c + 64][i + 1];
    }
    float r = ut;
    #pragma unroll
    for (int o = 1; o < 64; o <<= 1) r += __shfl_xor(r, o);
    if (c == 0) {
        float res = 1.0f;
        if (idx > 0)
            res = 1.0f + 0.6931471805599453f * ((float)Eacc + __log2f(r) + 7.0f * (float)idx);
        out[b] = res;
    }
}

extern "C" void kernel_launch(void* const* d_in, const int* in_sizes, int n_in,
                              void* d_out, int out_size, void* d_ws, size_t ws_size,
                              hipStream_t stream)
{
    const float* Y   = (const float*)d_in[0];
    const float* em  = (const float*)d_in[1];
    const int*   sl  = (const int*)d_in[2];
    const float* W1  = (const float*)d_in[3];
    const float* b1  = (const float*)d_in[4];
    const float* W2  = (const float*)d_in[5];
    const float* b2  = (const float*)d_in[6];
    const float* W3  = (const float*)d_in[7];
    const float* b3  = (const float*)d_in[8];
    float* out = (float*)d_out;
    char* ws = (char*)d_ws;

    __bf16* W1T  = (__bf16*)(ws + OFF_W1T);
    __bf16* W23B = (__bf16*)(ws + OFF_W23B);
    u16*    ts   = (u16*)(ws + OFF_TS);

    prep_kernel<<<164, 256, 0, stream>>>(W1, W2, W3, W1T, W23B);
    gemm1_kernel<<<512, 256, 0, stream>>>(Y, W1T, b1, ts);
    band_recur_kernel<<<128, 256, 0, stream>>>(ts, (const u16*)W23B, b2, b3, em, sl, out);
}